// Round 14
// baseline (497.139 us; speedup 1.0000x reference)
//
#include <hip/hip_runtime.h>

typedef __attribute__((ext_vector_type(4))) float f32x4;
typedef __attribute__((ext_vector_type(8))) short s16x8;
typedef __attribute__((ext_vector_type(4))) unsigned short u16x4;

__device__ __forceinline__ unsigned short f2bf(float x) {
  union { float f; unsigned u; } un; un.f = x;
  unsigned u = un.u;
  u += 0x7FFFu + ((u >> 16) & 1u);
  return (unsigned short)(u >> 16);
}
__device__ __forceinline__ float bf2f(unsigned short h) {
  union { unsigned u; float f; } un; un.u = ((unsigned)h) << 16; return un.f;
}

// Canonical accumulate form: D tied to C ("+v").
__device__ __forceinline__ f32x4 mfma16(s16x8 a, s16x8 b, f32x4 c) {
  asm("v_mfma_f32_16x16x32_bf16 %0, %1, %2, %0" : "+v"(c) : "v"(a), "v"(b));
  return c;
}

__device__ __forceinline__ void gld16(const void* g, void* l) {
  __builtin_amdgcn_global_load_lds(
      (const __attribute__((address_space(1))) void*)g,
      (__attribute__((address_space(3))) void*)l, 16, 0, 0);
}

// ---------------------------------------------------------------------------
// bf16 GEMM, m97-style (R11-proven, unchanged)
// ---------------------------------------------------------------------------
template<bool RELU, bool RESID, bool OUT_BF16>
__global__ __launch_bounds__(256, 2) void bgemm_k(
    const unsigned short* __restrict__ Ab, const unsigned short* __restrict__ Bb,
    const float* __restrict__ bias, const float* __restrict__ resid,
    void* __restrict__ Cp, int M, int N, int K, int lbx)
{
  __shared__ __align__(16) unsigned short As[2][128 * 64];
  __shared__ __align__(16) unsigned short Bs[2][128 * 64];

  const int nwg = gridDim.x;
  const int bid = blockIdx.x;
  const int swz = (bid & 7) * (nwg >> 3) + (bid >> 3);
  const int nbx_m1 = (1 << lbx) - 1;
  const int n0 = (swz & nbx_m1) * 128;
  const int m0 = (swz >> lbx) * 128;

  const int tid = threadIdx.x;
  const int lane = tid & 63;
  const int w = tid >> 6;
  const int wm = w >> 1, wn = w & 1;
  const int li = lane & 15, g = lane >> 4;

  f32x4 acc[4][4] = {};

#define STAGE(buf, kt) do { \
    const int k0_ = (kt) * 64; \
    _Pragma("unroll") \
    for (int i_ = 0; i_ < 4; i_++) { \
      int lin = i_ * 256 + tid; int row = lin >> 3; \
      int cg = (lin & 7) ^ (row & 7); \
      gld16(Ab + (size_t)(m0 + row) * K + k0_ + cg * 8, &As[buf][lin * 8]); \
    } \
    _Pragma("unroll") \
    for (int i_ = 0; i_ < 4; i_++) { \
      int lin = i_ * 256 + tid; int row = lin >> 3; \
      int cg = (lin & 7) ^ (row & 7); \
      gld16(Bb + (size_t)(n0 + row) * K + k0_ + cg * 8, &Bs[buf][lin * 8]); \
    } \
  } while (0)

  const int NT = K >> 6;
  STAGE(0, 0);
  for (int t = 0; t < NT; ++t) {
    const int cur = t & 1;
    if (t + 1 < NT) {
      STAGE(cur ^ 1, t + 1);
      asm volatile("s_waitcnt vmcnt(8)" ::: "memory");
    } else {
      asm volatile("s_waitcnt vmcnt(0)" ::: "memory");
    }
    __builtin_amdgcn_sched_barrier(0);
    __builtin_amdgcn_s_barrier();
    __builtin_amdgcn_sched_barrier(0);
#pragma unroll
    for (int ks = 0; ks < 2; ++ks) {
      s16x8 af[4], bf[4];
#pragma unroll
      for (int mt = 0; mt < 4; mt++) {
        int row = wm * 64 + mt * 16 + li;
        int slot = (4 * ks + g) ^ (row & 7);
        af[mt] = *(const s16x8*)&As[cur][row * 64 + slot * 8];
      }
#pragma unroll
      for (int nt = 0; nt < 4; nt++) {
        int row = wn * 64 + nt * 16 + li;
        int slot = (4 * ks + g) ^ (row & 7);
        bf[nt] = *(const s16x8*)&Bs[cur][row * 64 + slot * 8];
      }
#pragma unroll
      for (int mt = 0; mt < 4; mt++)
#pragma unroll
        for (int nt = 0; nt < 4; nt++)
          acc[mt][nt] = mfma16(af[mt], bf[nt], acc[mt][nt]);
    }
    __builtin_amdgcn_sched_barrier(0);
    __builtin_amdgcn_s_barrier();
    __builtin_amdgcn_sched_barrier(0);
  }
#undef STAGE

  asm volatile("s_nop 7\n\ts_nop 7" :::);
#pragma unroll
  for (int mt = 0; mt < 4; mt++) {
    int mrow = m0 + wm * 64 + mt * 16 + 4 * g;
#pragma unroll
    for (int nt = 0; nt < 4; nt++) {
      int ncol = n0 + wn * 64 + nt * 16 + li;
      float bv = bias ? bias[ncol] : 0.f;
#pragma unroll
      for (int r = 0; r < 4; r++) {
        int mr = mrow + r;
        float v = acc[mt][nt][r] + bv;
        if (RESID) v += resid[(size_t)mr * N + ncol];
        if (RELU) v = fmaxf(v, 0.f);
        if (OUT_BF16) ((unsigned short*)Cp)[(size_t)mr * N + ncol] = f2bf(v);
        else          ((float*)Cp)[(size_t)mr * N + ncol] = v;
      }
    }
  }
}

// ---------------------------------------------------------------------------
// Split-bf16 projection GEMM v3: bgemm double-buffer skeleton, BK=32.
// A/B hi+lo bf16 [.][K]; 2 bufs x 4 arrays x 128x32 = 64KB LDS; 8 gld16/iter
// -> counted vmcnt(8). Accumulation order bitwise-identical to v2.
// A2/C2 M-stacking kept (CA merge).
// ---------------------------------------------------------------------------
__global__ __launch_bounds__(256, 2) void sgemm_k(
    const unsigned short* __restrict__ Ah, const unsigned short* __restrict__ Al,
    const unsigned short* __restrict__ A2h, const unsigned short* __restrict__ A2l,
    const unsigned short* __restrict__ Bh, const unsigned short* __restrict__ Bl,
    const float* __restrict__ bias,
    unsigned short* __restrict__ Cb, unsigned short* __restrict__ C2b,
    int Ms, int M, int N, int K, int lbx)
{
  __shared__ __align__(16) unsigned short AsH[2][128 * 32];
  __shared__ __align__(16) unsigned short AsL[2][128 * 32];
  __shared__ __align__(16) unsigned short BsH[2][128 * 32];
  __shared__ __align__(16) unsigned short BsL[2][128 * 32];

  const int nwg = gridDim.x;
  const int bid = blockIdx.x;
  const int swz = (bid & 7) * (nwg >> 3) + (bid >> 3);
  const int nbx_m1 = (1 << lbx) - 1;
  const int n0 = (swz & nbx_m1) * 128;
  int m0 = (swz >> lbx) * 128;

  const unsigned short* Ahp = Ah;
  const unsigned short* Alp = Al;
  unsigned short* Cp = Cb;
  if (m0 >= Ms) { Ahp = A2h; Alp = A2l; Cp = C2b; m0 -= Ms; }

  const int tid = threadIdx.x;
  const int lane = tid & 63;
  const int w = tid >> 6;
  const int wm = w >> 1, wn = w & 1;
  const int li = lane & 15, g = lane >> 4;

  f32x4 acc[4][4] = {};

#define SSTAGE(buf, kt) do { \
    const int k0_ = (kt) * 32; \
    _Pragma("unroll") \
    for (int i_ = 0; i_ < 2; i_++) { \
      int lin = i_ * 256 + tid; int row = lin >> 2; \
      int cg = (lin & 3) ^ (row & 3); \
      size_t offA = (size_t)(m0 + row) * K + k0_ + cg * 8; \
      size_t offB = (size_t)(n0 + row) * K + k0_ + cg * 8; \
      gld16(Ahp + offA, &AsH[buf][lin * 8]); \
      gld16(Alp + offA, &AsL[buf][lin * 8]); \
      gld16(Bh + offB, &BsH[buf][lin * 8]); \
      gld16(Bl + offB, &BsL[buf][lin * 8]); \
    } \
  } while (0)

  const int NT = K >> 5;
  SSTAGE(0, 0);
  for (int t = 0; t < NT; ++t) {
    const int cur = t & 1;
    if (t + 1 < NT) {
      SSTAGE(cur ^ 1, t + 1);
      asm volatile("s_waitcnt vmcnt(8)" ::: "memory");
    } else {
      asm volatile("s_waitcnt vmcnt(0)" ::: "memory");
    }
    __builtin_amdgcn_sched_barrier(0);
    __builtin_amdgcn_s_barrier();
    __builtin_amdgcn_sched_barrier(0);
    {
      s16x8 ah[4], al[4], bh[4], bl[4];
#pragma unroll
      for (int mt = 0; mt < 4; mt++) {
        int row = wm * 64 + mt * 16 + li;
        int slot = g ^ (row & 3);
        ah[mt] = *(const s16x8*)&AsH[cur][row * 32 + slot * 8];
        al[mt] = *(const s16x8*)&AsL[cur][row * 32 + slot * 8];
      }
#pragma unroll
      for (int nt = 0; nt < 4; nt++) {
        int row = wn * 64 + nt * 16 + li;
        int slot = g ^ (row & 3);
        bh[nt] = *(const s16x8*)&BsH[cur][row * 32 + slot * 8];
        bl[nt] = *(const s16x8*)&BsL[cur][row * 32 + slot * 8];
      }
#pragma unroll
      for (int mt = 0; mt < 4; mt++)
#pragma unroll
        for (int nt = 0; nt < 4; nt++) {
          acc[mt][nt] = mfma16(ah[mt], bh[nt], acc[mt][nt]);
          acc[mt][nt] = mfma16(ah[mt], bl[nt], acc[mt][nt]);
          acc[mt][nt] = mfma16(al[mt], bh[nt], acc[mt][nt]);
        }
    }
    __builtin_amdgcn_sched_barrier(0);
    __builtin_amdgcn_s_barrier();
    __builtin_amdgcn_sched_barrier(0);
  }
#undef SSTAGE

  asm volatile("s_nop 7\n\ts_nop 7" :::);
#pragma unroll
  for (int mt = 0; mt < 4; mt++) {
    int mrow = m0 + wm * 64 + mt * 16 + 4 * g;
#pragma unroll
    for (int nt = 0; nt < 4; nt++) {
      int ncol = n0 + wn * 64 + nt * 16 + li;
      float bv = bias[ncol];
#pragma unroll
      for (int r = 0; r < 4; r++) {
        int mr = mrow + r;
        Cp[(size_t)mr * N + ncol] = f2bf(acc[mt][nt][r] + bv);
      }
    }
  }
}

// ---------------------------------------------------------------------------
// Fused weight pre-pass (block-range dispatch)
// ---------------------------------------------------------------------------
__device__ __forceinline__ void dev_tc(const float* __restrict__ W,
    unsigned short* __restrict__ WT, int K, int N, int bid, char* ldsu)
{
  unsigned short (*Ls)[65] = (unsigned short (*)[65])ldsu;
  int ntx = N >> 6;
  int ty = bid / ntx, tx = bid - ty * ntx;
  int r0 = ty << 6, c0 = tx << 6;
  int tid = threadIdx.x;
  int rl = tid >> 4, cl = (tid & 15) << 2;
#pragma unroll
  for (int rr = 0; rr < 4; rr++) {
    f32x4 v = *(const f32x4*)&W[(size_t)(r0 + rl + rr * 16) * N + c0 + cl];
#pragma unroll
    for (int j = 0; j < 4; j++) Ls[rl + rr * 16][cl + j] = f2bf(v[j]);
  }
  __syncthreads();
#pragma unroll
  for (int rr = 0; rr < 4; rr++) {
    int nl = rl + rr * 16;
    u16x4 o;
#pragma unroll
    for (int j = 0; j < 4; j++) o[j] = Ls[cl + j][nl];
    *(u16x4*)&WT[(size_t)(c0 + nl) * K + r0 + cl] = o;
  }
}

__device__ __forceinline__ void dev_tc2(const float* __restrict__ W,
    unsigned short* __restrict__ WTh, unsigned short* __restrict__ WTl,
    int K, int N, int bid, char* ldsu)
{
  float (*Ls)[65] = (float (*)[65])ldsu;
  int ntx = N >> 6;
  int ty = bid / ntx, tx = bid - ty * ntx;
  int r0 = ty << 6, c0 = tx << 6;
  int tid = threadIdx.x;
  int rl = tid >> 4, cl = (tid & 15) << 2;
#pragma unroll
  for (int rr = 0; rr < 4; rr++) {
    f32x4 v = *(const f32x4*)&W[(size_t)(r0 + rl + rr * 16) * N + c0 + cl];
#pragma unroll
    for (int j = 0; j < 4; j++) Ls[rl + rr * 16][cl + j] = v[j];
  }
  __syncthreads();
#pragma unroll
  for (int rr = 0; rr < 4; rr++) {
    int nl = rl + rr * 16;
    u16x4 oh, ol;
#pragma unroll
    for (int j = 0; j < 4; j++) {
      float v = Ls[cl + j][nl];
      unsigned short h = f2bf(v);
      oh[j] = h; ol[j] = f2bf(v - bf2f(h));
    }
    *(u16x4*)&WTh[(size_t)(c0 + nl) * K + r0 + cl] = oh;
    *(u16x4*)&WTl[(size_t)(c0 + nl) * K + r0 + cl] = ol;
  }
}

__global__ __launch_bounds__(256) void prep_w_k(
    const float* saWq, const float* caWq, const float* saWo, const float* caWo,
    const float* W1, const float* W2,
    unsigned short* WqTsaH, unsigned short* WqTsaL,
    unsigned short* WqTcaH, unsigned short* WqTcaL,
    unsigned short* WoTsa, unsigned short* WoTca,
    unsigned short* W1T, unsigned short* W2T)
{
  __shared__ __align__(16) char LDSU[64 * 65 * 4];
  int bid = blockIdx.x;
  if (bid < 256)       dev_tc2(saWq, WqTsaH, WqTsaL, 1024, 1024, bid, LDSU);
  else if (bid < 512)  dev_tc2(caWq, WqTcaH, WqTcaL, 1024, 1024, bid - 256, LDSU);
  else if (bid < 768)  dev_tc (saWo, WoTsa, 1024, 1024, bid - 512, LDSU);
  else if (bid < 1024) dev_tc (caWo, WoTca, 1024, 1024, bid - 768, LDSU);
  else if (bid < 2048) dev_tc (W1, W1T, 1024, 4096, bid - 1024, LDSU);
  else                 dev_tc (W2, W2T, 4096, 1024, bid - 2048, LDSU);
}

// ---------------------------------------------------------------------------
// Fused activation pre-pass
// ---------------------------------------------------------------------------
__device__ __forceinline__ void dev_cvt2row(const float* __restrict__ X,
    unsigned short* __restrict__ H, unsigned short* __restrict__ L, int bid)
{
  int i = (bid * 256 + threadIdx.x) * 4;
  f32x4 v = *(const f32x4*)&X[i];
  u16x4 hh, ll;
#pragma unroll
  for (int j = 0; j < 4; j++) {
    unsigned short h = f2bf(v[j]);
    hh[j] = h; ll[j] = f2bf(v[j] - bf2f(h));
  }
  *(u16x4*)&H[i] = hh;
  *(u16x4*)&L[i] = ll;
}

__device__ __forceinline__ void dev_wrel(const float* __restrict__ Wq,
    float* __restrict__ Wr, int bid)
{
  int idx = bid * 256 + threadIdx.x;
  int k = idx >> 4, h = idx & 15;
  const float* src = Wq + (size_t)k * 1024 + h * 64;
  float a = 0.f, s = 0.f;
#pragma unroll
  for (int d = 0; d < 64; d += 4) {
    f32x4 v = *(const f32x4*)&src[d];
#pragma unroll
    for (int j = 0; j < 4; j++) { a += v[j] * (float)(d + j + 1024); s += v[j]; }
  }
  Wr[k * 32 + h] = a;
  Wr[k * 32 + 16 + h] = s;
}

__device__ __forceinline__ void dev_crel(const float* __restrict__ bq,
    float* __restrict__ cr)
{
  int h = threadIdx.x;
  if (h < 16) {
    float a = 0.f, s = 0.f;
    for (int d = 0; d < 64; d++) { float v = bq[h * 64 + d]; a += v * (float)(d + 1024); s += v; }
    cr[h] = a; cr[16 + h] = s;
  }
}

__global__ __launch_bounds__(256) void prep_a_k(
    const float* tgt, const float* mem,
    unsigned short* tgth, unsigned short* tgtl,
    unsigned short* memh, unsigned short* meml,
    const float* saWq, const float* caWq, float* wrelsa, float* wrelca,
    const float* sabq, const float* cabq, float* crelsa, float* crelca)
{
  int bid = blockIdx.x;
  if (bid < 4096)       dev_cvt2row(tgt, tgth, tgtl, bid);
  else if (bid < 8192)  dev_cvt2row(mem, memh, meml, bid - 4096);
  else if (bid < 8256)  dev_wrel(saWq, wrelsa, bid - 8192);
  else if (bid < 8320)  dev_wrel(caWq, wrelca, bid - 8256);
  else if (bid == 8320) dev_crel(sabq, crelsa);
  else                  dev_crel(cabq, crelca);
}

// ---------------------------------------------------------------------------
// rel coefficients mini-GEMM (f32-exact): Out[4096][32] = X[4096][1024]@Wr + cr
// ---------------------------------------------------------------------------
__global__ __launch_bounds__(256) void relgemm_k(const float* __restrict__ X,
    const float* __restrict__ Wr, const float* __restrict__ cr,
    float* __restrict__ Out)
{
  __shared__ float Xs[8][256];
  __shared__ float Ws[256][32];
  int r0 = blockIdx.x * 8;
  int tid = threadIdx.x;
  int rl = tid >> 5, col = tid & 31;
  float acc = 0.f;
  for (int kc = 0; kc < 1024; kc += 256) {
    __syncthreads();
    {
      const float* xs = X + (size_t)(r0 + rl) * 1024 + kc + col * 8;
      *(f32x4*)&Xs[rl][col * 8] = *(const f32x4*)xs;
      *(f32x4*)&Xs[rl][col * 8 + 4] = *(const f32x4*)(xs + 4);
    }
    {
      const float* wsrc = Wr + (size_t)(kc + tid) * 32;
#pragma unroll
      for (int i = 0; i < 8; i++) *(f32x4*)&Ws[tid][i * 4] = *(const f32x4*)&wsrc[i * 4];
    }
    __syncthreads();
#pragma unroll 8
    for (int kk = 0; kk < 256; ++kk) acc += Xs[rl][kk] * Ws[kk][col];
  }
  Out[(size_t)(r0 + rl) * 32 + col] = acc + cr[col];
}

// ---------------------------------------------------------------------------
// Fused attention — R11-proven body VERBATIM. FROZEN.
// ---------------------------------------------------------------------------
template<bool CAUSAL>
__global__ __launch_bounds__(512) void attn_k(
    const unsigned short* __restrict__ Qb, const unsigned short* __restrict__ KVb,
    const float* __restrict__ rAS, unsigned short* __restrict__ Ob)
{
  const int bh = blockIdx.x;
  const int b = bh >> 4, h = bh & 15;
  const int y = blockIdx.y;               // 0..7
  const int tid = threadIdx.x, lane = tid & 63, w = tid >> 6;
  const int g = lane >> 4, li = lane & 15;

  __shared__ __align__(16) unsigned short Kt[64 * 64];   // [k][d] swizzled
  __shared__ __align__(16) unsigned short KT[64 * 64];   // [d][k] swizzled
  __shared__ __align__(16) unsigned short Pl[8][16 * 64];

  const int tile = CAUSAL ? ((w < 4) ? y : (15 - y)) : (2 * y + (w >> 2));
  const int q0 = tile * 64 + (w & 3) * 16;
  const int nkb = CAUSAL ? (16 - y) : 16;

  s16x8 qf[2];
  {
    const unsigned short* qrow = Qb + (size_t)(b * 1024 + q0 + li) * 1024 + h * 64;
    qf[0] = *(const s16x8*)&qrow[8 * g];
    qf[1] = *(const s16x8*)&qrow[8 * g + 32];
  }
  const float SCL2 = 0.125f * 1.44269504f;
  int qri[4];
  float C0c[4], C1c[4], rSc[4], rS1c[4];
#pragma unroll
  for (int r = 0; r < 4; r++) {
    int qr = q0 + 4 * g + r;
    qri[r] = qr;
    float rA = rAS[(size_t)(b * 1024 + qr) * 32 + h];
    float rS = rAS[(size_t)(b * 1024 + qr) * 32 + 16 + h];
    int q1 = (qr + 1 < 1024) ? qr + 1 : 1023;
    float rA1 = rAS[(size_t)(b * 1024 + q1) * 32 + h];
    float rS1 = rAS[(size_t)(b * 1024 + q1) * 32 + 16 + h];
    C0c[r]  = (rA + (float)(qr - 1023) * rS) * SCL2;
    rSc[r]  = rS * SCL2;
    C1c[r]  = (rA1 + (float)(qr + 2) * rS1) * SCL2;
    rS1c[r] = rS1 * SCL2;
  }

  float mrow[4], lrow[4];
#pragma unroll
  for (int r = 0; r < 4; r++) { mrow[r] = -3.0e38f; lrow[r] = 0.f; }
  f32x4 accO[4] = {};

  for (int kbk = 0; kbk < nkb; kbk++) {
    __syncthreads();
    // ---- stage K[k][d] + KT[d][k]: krow = lane, dcols = w*8..w*8+7 ----
    {
      const unsigned short* src = KVb + (size_t)(b * 1024 + kbk * 64 + lane) * 1024 + h * 64 + w * 8;
      s16x8 v = *(const s16x8*)src;
      int slot = w ^ (lane & 7);
      *(s16x8*)&Kt[lane * 64 + slot * 8] = v;
#pragma unroll
      for (int j = 0; j < 8; j++) {
        int d = w * 8 + j;
        KT[d * 64 + (((lane >> 3) ^ (d & 7)) * 8) + (lane & 7)] = (unsigned short)v[j];
      }
    }
    __syncthreads();
    if (!CAUSAL || kbk <= tile) {
      const bool diag = CAUSAL && (kbk == tile);
      // S = Q K^T
      f32x4 accS[4];
#pragma unroll
      for (int nt = 0; nt < 4; nt++) {
        int krow = li + 16 * nt;
        f32x4 c = {};
#pragma unroll
        for (int ks = 0; ks < 2; ks++) {
          int slot = (g + 4 * ks) ^ (krow & 7);
          s16x8 kf = *(const s16x8*)&Kt[krow * 64 + slot * 8];
          c = mfma16(qf[ks], kf, c);
        }
        accS[nt] = c;
      }
      // skew + (diag) mask + online softmax (log2 domain)
      float pv[4][4];
      float bm[4];
#pragma unroll
      for (int r = 0; r < 4; r++) bm[r] = -3.0e38f;
#pragma unroll
      for (int nt = 0; nt < 4; nt++) {
        int kk = kbk * 64 + 16 * nt + li;
        float kkf = (float)kk;
#pragma unroll
        for (int r = 0; r < 4; r++) {
          float sk = (kk <= qri[r]) ? fmaf(kkf, -rSc[r], C0c[r])
                   : ((kk == qri[r] + 1) ? 0.f : fmaf(kkf, -rS1c[r], C1c[r]));
          float lg = fmaf(accS[nt][r], SCL2, sk);
          if (diag && kk > qri[r]) lg = -1.0e9f;
          pv[nt][r] = lg;
          bm[r] = fmaxf(bm[r], lg);
        }
      }
#pragma unroll
      for (int off = 1; off < 16; off <<= 1)
#pragma unroll
        for (int r = 0; r < 4; r++)
          bm[r] = fmaxf(bm[r], __shfl_xor(bm[r], off, 64));
      float scl[4], rsum[4];
#pragma unroll
      for (int r = 0; r < 4; r++) {
        float mnew = fmaxf(mrow[r], bm[r]);
        scl[r] = exp2f(mrow[r] - mnew);
        mrow[r] = mnew;
        rsum[r] = 0.f;
      }
#pragma unroll
      for (int nt = 0; nt < 4; nt++)
#pragma unroll
        for (int r = 0; r < 4; r++) {
          float p = exp2f(pv[nt][r] - mrow[r]);
          pv[nt][r] = p;
          rsum[r] += p;
        }
#pragma unroll
      for (int off = 1; off < 16; off <<= 1)
#pragma unroll
        for (int r = 0; r < 4; r++)
          rsum[r] += __shfl_xor(rsum[r], off, 64);
#pragma unroll
      for (int r = 0; r < 4; r++) lrow[r] = lrow[r] * scl[r] + rsum[r];
      // write P (bf16) to per-wave LDS
#pragma unroll
      for (int nt = 0; nt < 4; nt++)
#pragma unroll
        for (int r = 0; r < 4; r++) {
          int qq = 4 * g + r;
          int kkk = 16 * nt + li;
          int slot = (kkk >> 3) ^ (qq & 7);
          Pl[w][qq * 64 + slot * 8 + (kkk & 7)] = f2bf(pv[nt][r]);
        }
      // rescale O
#pragma unroll
      for (int dt = 0; dt < 4; dt++)
#pragma unroll
        for (int r = 0; r < 4; r++) accO[dt][r] *= scl[r];
      // P fragments (per-wave LDS; same-wave RAW ordering in DS pipe)
      s16x8 pfk[2];
#pragma unroll
      for (int ks = 0; ks < 2; ks++) {
        int slotA = (g + 4 * ks) ^ (li & 7);
        pfk[ks] = *(const s16x8*)&Pl[w][li * 64 + slotA * 8];
      }
      // O += P @ V  (V == K; B-frag from KT[d][k])
#pragma unroll
      for (int dt = 0; dt < 4; dt++) {
#pragma unroll
        for (int ks = 0; ks < 2; ks++) {
          int drow = li + 16 * dt;
          int slotB = (g + 4 * ks) ^ (drow & 7);
          s16x8 vf = *(const s16x8*)&KT[drow * 64 + slotB * 8];
          accO[dt] = mfma16(pfk[ks], vf, accO[dt]);
        }
      }
    }
  }
  // epilogue: O / l -> bf16
  asm volatile("s_nop 7\n\ts_nop 7" :::);
#pragma unroll
  for (int dt = 0; dt < 4; dt++) {
    int dcol = h * 64 + li + 16 * dt;
#pragma unroll
    for (int r = 0; r < 4; r++) {
      int q = q0 + 4 * g + r;
      Ob[(size_t)(b * 1024 + q) * 1024 + dcol] = f2bf(accO[dt][r] / lrow[r]);
    }
  }
}

// ---------------------------------------------------------------------------
// LayerNorm rows of 1024; writes f32 and optional bf16 hi (+ optional lo).
// ---------------------------------------------------------------------------
__global__ __launch_bounds__(256) void ln_k(const float* __restrict__ X,
    const float* __restrict__ gw, const float* __restrict__ bw,
    float* __restrict__ O, unsigned short* __restrict__ Obh,
    unsigned short* __restrict__ Obl)
{
  int row = blockIdx.x;
  const float* x = X + (size_t)row * 1024;
  int tid = threadIdx.x;
  f32x4 v = *(const f32x4*)&x[tid * 4];
  float s = v[0] + v[1] + v[2] + v[3];
  float s2 = v[0]*v[0] + v[1]*v[1] + v[2]*v[2] + v[3]*v[3];
#pragma unroll
  for (int off = 32; off > 0; off >>= 1) {
    s += __shfl_down(s, off, 64);
    s2 += __shfl_down(s2, off, 64);
  }
  __shared__ float rb[8];
  if ((tid & 63) == 0) { rb[tid >> 6] = s; rb[4 + (tid >> 6)] = s2; }
  __syncthreads();
  float S = rb[0] + rb[1] + rb[2] + rb[3];
  float S2 = rb[4] + rb[5] + rb[6] + rb[7];
  float mu = S * (1.f / 1024.f);
  float var = S2 * (1.f / 1024.f) - mu * mu;
  float rstd = rsqrtf(var + 1e-5f);
  f32x4 go = *(const f32x4*)&gw[tid * 4];
  f32x4 bo = *(const f32x4*)&bw[tid * 4];
  f32x4 r;
#pragma unroll
  for (int j = 0; j < 4; j++) r[j] = (v[j] - mu) * rstd * go[j] + bo[j];
  *(f32x4*)&O[(size_t)row * 1024 + tid * 4] = r;
  if (Obh) {
    u16x4 oh;
#pragma unroll
    for (int j = 0; j < 4; j++) oh[j] = f2bf(r[j]);
    *(u16x4*)&Obh[(size_t)row * 1024 + tid * 4] = oh;
    if (Obl) {
      u16x4 ol;
#pragma unroll
      for (int j = 0; j < 4; j++) ol[j] = f2bf(r[j] - bf2f(f2bf(r[j])));
      *(u16x4*)&Obl[(size_t)row * 1024 + tid * 4] = ol;
    }
  }
}

// ---------------------------------------------------------------------------
extern "C" void kernel_launch(void* const* d_in, const int* in_sizes, int n_in,
                              void* d_out, int out_size, void* d_ws, size_t ws_size,
                              hipStream_t stream)
{
  const float* tgt  = (const float*)d_in[0];
  const float* mem  = (const float*)d_in[1];
  const float* saWq = (const float*)d_in[3];
  const float* sabq = (const float*)d_in[4];
  const float* saWo = (const float*)d_in[5];
  const float* sabo = (const float*)d_in[6];
  const float* caWq = (const float*)d_in[7];
  const float* cabq = (const float*)d_in[8];
  const float* caWo = (const float*)d_in[9];
  const float* cabo = (const float*)d_in[10];
  const float* W1   = (const float*)d_in[11];
  const float* b1   = (const float*)d_in[12];
  const float* W2   = (const float*)d_in[13];
  const float* b2   = (const float*)d_in[14];
  const float* g1   = (const float*)d_in[15];
  const float* be1  = (const float*)d_in[16];
  const float* g2   = (const float*)d_in[17];
  const float* be2  = (const float*)d_in[18];
  const float* g3   = (const float*)d_in[19];
  const float* be3  = (const float*)d_in[20];
  float* out = (float*)d_out;

  char* ws = (char*)d_ws;
  const size_t ACT = (size_t)4096 * 1024;
  unsigned short* RA   = (unsigned short*)ws; ws += ACT * 2;  // tgth -> attnb(SA) -> x1h -> attnb(CA)
  unsigned short* RB   = (unsigned short*)ws; ws += ACT * 2;  // tgtl -> x1l
  unsigned short* qkvb = (unsigned short*)ws; ws += ACT * 2;  // SA qkv -> CA q
  unsigned short* kvb  = (unsigned short*)ws; ws += ACT * 2;  // CA kv
  unsigned short* x2b  = (unsigned short*)ws; ws += ACT * 2;
  unsigned short* RF   = (unsigned short*)ws; ws += (size_t)4096 * 4096 * 2; // memh+meml -> hb
  unsigned short* memh = RF;
  unsigned short* meml = RF + ACT;
  unsigned short* hb   = RF;
  unsigned short* WqTsaH = (unsigned short*)ws; ws += (size_t)1024 * 1024 * 2;
  unsigned short* WqTsaL = (unsigned short*)ws; ws += (size_t)1024 * 1024 * 2;
  unsigned short* WoTsa  = (unsigned short*)ws; ws += (size_t)1024 * 1024 * 2;
  unsigned short* WqTcaH = (unsigned short*)ws; ws += (size_t)1024 * 1024 * 2;
  unsigned short* WqTcaL = (unsigned short*)ws; ws += (size_t)1024 * 1024 * 2;
  unsigned short* WoTca  = (unsigned short*)ws; ws += (size_t)1024 * 1024 * 2;
  unsigned short* W1T = (unsigned short*)ws; ws += (size_t)4096 * 1024 * 2;
  unsigned short* W2T = (unsigned short*)ws; ws += (size_t)4096 * 1024 * 2;
  float* x2f = (float*)ws; ws += (size_t)4096 * 1024 * 4;
  float* rAS = (float*)ws; ws += (size_t)4096 * 32 * 4;
  float* wrelsa = (float*)ws; ws += (size_t)1024 * 32 * 4;
  float* wrelca = (float*)ws; ws += (size_t)1024 * 32 * 4;
  float* crelsa = (float*)ws; ws += 128;
  float* crelca = (float*)ws; ws += 128;
  float* x1f = out;   // d_out doubles as x1 f32 scratch

  dim3 blk(256);

  // ---------------- fused pre-pass (2 launches) ----------------
  prep_w_k<<<dim3(3072), blk, 0, stream>>>(saWq, caWq, saWo, caWo, W1, W2,
      WqTsaH, WqTsaL, WqTcaH, WqTcaL, WoTsa, WoTca, W1T, W2T);
  prep_a_k<<<dim3(8322), blk, 0, stream>>>(tgt, mem, RA, RB, memh, meml,
      saWq, caWq, wrelsa, wrelca, sabq, cabq, crelsa, crelca);

  // ---------------- main pipeline ----------------
  sgemm_k<<<dim3(256), blk, 0, stream>>>(RA, RB, RA, RB, WqTsaH, WqTsaL, sabq,
      qkvb, qkvb, 1 << 30, 4096, 1024, 1024, 3);
  relgemm_k<<<dim3(512), blk, 0, stream>>>(tgt, wrelsa, crelsa, rAS);
  attn_k<true><<<dim3(64, 8), dim3(512), 0, stream>>>(qkvb, qkvb, rAS, RA);   // attnb = RA
  bgemm_k<false, true, false><<<dim3(256), blk, 0, stream>>>(RA, WoTsa, sabo, tgt, x1f, 4096, 1024, 1024, 3);
  ln_k<<<dim3(4096), blk, 0, stream>>>(x1f, g1, be1, x1f, RA, RB);            // x1h = RA, x1l = RB
  // CA projections merged: q (rows 0..4095, A=x1) + kv (rows 4096.., A=mem)
  sgemm_k<<<dim3(512), blk, 0, stream>>>(RA, RB, memh, meml, WqTcaH, WqTcaL, cabq,
      qkvb, kvb, 4096, 8192, 1024, 1024, 3);
  relgemm_k<<<dim3(512), blk, 0, stream>>>(x1f, wrelca, crelca, rAS);
  attn_k<false><<<dim3(64, 8), dim3(512), 0, stream>>>(qkvb, kvb, rAS, RA);   // attnb = RA
  bgemm_k<false, true, false><<<dim3(256), blk, 0, stream>>>(RA, WoTca, cabo, x1f, x2f, 4096, 1024, 1024, 3);
  ln_k<<<dim3(4096), blk, 0, stream>>>(x2f, g2, be2, x2f, x2b, nullptr);
  // FFN (hb overwrites memh/meml region — dead after CA kv projection)
  bgemm_k<true, false, true><<<dim3(1024), blk, 0, stream>>>(x2b, W1T, b1, nullptr, hb, 4096, 4096, 1024, 5);
  bgemm_k<false, true, false><<<dim3(256), blk, 0, stream>>>(hb, W2T, b2, x2f, out, 4096, 1024, 4096, 3);
  ln_k<<<dim3(4096), blk, 0, stream>>>(out, g3, be3, out, nullptr, nullptr);

  (void)in_sizes; (void)n_in; (void)out_size; (void)ws_size;
}

// Round 15
// 459.175 us; speedup vs baseline: 1.0827x; 1.0827x over previous
//
#include <hip/hip_runtime.h>

typedef __attribute__((ext_vector_type(4))) float f32x4;
typedef __attribute__((ext_vector_type(8))) short s16x8;
typedef __attribute__((ext_vector_type(4))) unsigned short u16x4;

__device__ __forceinline__ unsigned short f2bf(float x) {
  union { float f; unsigned u; } un; un.f = x;
  unsigned u = un.u;
  u += 0x7FFFu + ((u >> 16) & 1u);
  return (unsigned short)(u >> 16);
}
__device__ __forceinline__ float bf2f(unsigned short h) {
  union { unsigned u; float f; } un; un.u = ((unsigned)h) << 16; return un.f;
}

// Canonical accumulate form: D tied to C ("+v").
__device__ __forceinline__ f32x4 mfma16(s16x8 a, s16x8 b, f32x4 c) {
  asm("v_mfma_f32_16x16x32_bf16 %0, %1, %2, %0" : "+v"(c) : "v"(a), "v"(b));
  return c;
}

__device__ __forceinline__ void gld16(const void* g, void* l) {
  __builtin_amdgcn_global_load_lds(
      (const __attribute__((address_space(1))) void*)g,
      (__attribute__((address_space(3))) void*)l, 16, 0, 0);
}

// ---------------------------------------------------------------------------
// bf16 GEMM, m97-style (R11-proven, unchanged)
// ---------------------------------------------------------------------------
template<bool RELU, bool RESID, bool OUT_BF16>
__global__ __launch_bounds__(256, 2) void bgemm_k(
    const unsigned short* __restrict__ Ab, const unsigned short* __restrict__ Bb,
    const float* __restrict__ bias, const float* __restrict__ resid,
    void* __restrict__ Cp, int M, int N, int K, int lbx)
{
  __shared__ __align__(16) unsigned short As[2][128 * 64];
  __shared__ __align__(16) unsigned short Bs[2][128 * 64];

  const int nwg = gridDim.x;
  const int bid = blockIdx.x;
  const int swz = (bid & 7) * (nwg >> 3) + (bid >> 3);
  const int nbx_m1 = (1 << lbx) - 1;
  const int n0 = (swz & nbx_m1) * 128;
  const int m0 = (swz >> lbx) * 128;

  const int tid = threadIdx.x;
  const int lane = tid & 63;
  const int w = tid >> 6;
  const int wm = w >> 1, wn = w & 1;
  const int li = lane & 15, g = lane >> 4;

  f32x4 acc[4][4] = {};

#define STAGE(buf, kt) do { \
    const int k0_ = (kt) * 64; \
    _Pragma("unroll") \
    for (int i_ = 0; i_ < 4; i_++) { \
      int lin = i_ * 256 + tid; int row = lin >> 3; \
      int cg = (lin & 7) ^ (row & 7); \
      gld16(Ab + (size_t)(m0 + row) * K + k0_ + cg * 8, &As[buf][lin * 8]); \
    } \
    _Pragma("unroll") \
    for (int i_ = 0; i_ < 4; i_++) { \
      int lin = i_ * 256 + tid; int row = lin >> 3; \
      int cg = (lin & 7) ^ (row & 7); \
      gld16(Bb + (size_t)(n0 + row) * K + k0_ + cg * 8, &Bs[buf][lin * 8]); \
    } \
  } while (0)

  const int NT = K >> 6;
  STAGE(0, 0);
  for (int t = 0; t < NT; ++t) {
    const int cur = t & 1;
    if (t + 1 < NT) {
      STAGE(cur ^ 1, t + 1);
      asm volatile("s_waitcnt vmcnt(8)" ::: "memory");
    } else {
      asm volatile("s_waitcnt vmcnt(0)" ::: "memory");
    }
    __builtin_amdgcn_sched_barrier(0);
    __builtin_amdgcn_s_barrier();
    __builtin_amdgcn_sched_barrier(0);
#pragma unroll
    for (int ks = 0; ks < 2; ++ks) {
      s16x8 af[4], bf[4];
#pragma unroll
      for (int mt = 0; mt < 4; mt++) {
        int row = wm * 64 + mt * 16 + li;
        int slot = (4 * ks + g) ^ (row & 7);
        af[mt] = *(const s16x8*)&As[cur][row * 64 + slot * 8];
      }
#pragma unroll
      for (int nt = 0; nt < 4; nt++) {
        int row = wn * 64 + nt * 16 + li;
        int slot = (4 * ks + g) ^ (row & 7);
        bf[nt] = *(const s16x8*)&Bs[cur][row * 64 + slot * 8];
      }
#pragma unroll
      for (int mt = 0; mt < 4; mt++)
#pragma unroll
        for (int nt = 0; nt < 4; nt++)
          acc[mt][nt] = mfma16(af[mt], bf[nt], acc[mt][nt]);
    }
    __builtin_amdgcn_sched_barrier(0);
    __builtin_amdgcn_s_barrier();
    __builtin_amdgcn_sched_barrier(0);
  }
#undef STAGE

  asm volatile("s_nop 7\n\ts_nop 7" :::);
#pragma unroll
  for (int mt = 0; mt < 4; mt++) {
    int mrow = m0 + wm * 64 + mt * 16 + 4 * g;
#pragma unroll
    for (int nt = 0; nt < 4; nt++) {
      int ncol = n0 + wn * 64 + nt * 16 + li;
      float bv = bias ? bias[ncol] : 0.f;
#pragma unroll
      for (int r = 0; r < 4; r++) {
        int mr = mrow + r;
        float v = acc[mt][nt][r] + bv;
        if (RESID) v += resid[(size_t)mr * N + ncol];
        if (RELU) v = fmaxf(v, 0.f);
        if (OUT_BF16) ((unsigned short*)Cp)[(size_t)mr * N + ncol] = f2bf(v);
        else          ((float*)Cp)[(size_t)mr * N + ncol] = v;
      }
    }
  }
}

// ---------------------------------------------------------------------------
// Split-K bgemm for FFN2: same skeleton; blocks with m-tile >= M/128 handle
// K-range [KH,2*KH) and write partial P1; else [0,KH) -> P0. f32 partials.
// ---------------------------------------------------------------------------
__global__ __launch_bounds__(256, 2) void bgemm_pk(
    const unsigned short* __restrict__ Ab, const unsigned short* __restrict__ Bb,
    float* __restrict__ P0, float* __restrict__ P1,
    int M, int N, int K, int KH, int lbx)
{
  __shared__ __align__(16) unsigned short As[2][128 * 64];
  __shared__ __align__(16) unsigned short Bs[2][128 * 64];

  const int nwg = gridDim.x;
  const int bid = blockIdx.x;
  const int swz = (bid & 7) * (nwg >> 3) + (bid >> 3);
  const int nbx_m1 = (1 << lbx) - 1;
  const int n0 = (swz & nbx_m1) * 128;
  int m0 = (swz >> lbx) * 128;

  int kb = 0;
  float* Pp = P0;
  if (m0 >= M) { m0 -= M; kb = KH; Pp = P1; }

  const int tid = threadIdx.x;
  const int lane = tid & 63;
  const int w = tid >> 6;
  const int wm = w >> 1, wn = w & 1;
  const int li = lane & 15, g = lane >> 4;

  f32x4 acc[4][4] = {};

#define PSTAGE(buf, kt) do { \
    const int k0_ = kb + (kt) * 64; \
    _Pragma("unroll") \
    for (int i_ = 0; i_ < 4; i_++) { \
      int lin = i_ * 256 + tid; int row = lin >> 3; \
      int cg = (lin & 7) ^ (row & 7); \
      gld16(Ab + (size_t)(m0 + row) * K + k0_ + cg * 8, &As[buf][lin * 8]); \
    } \
    _Pragma("unroll") \
    for (int i_ = 0; i_ < 4; i_++) { \
      int lin = i_ * 256 + tid; int row = lin >> 3; \
      int cg = (lin & 7) ^ (row & 7); \
      gld16(Bb + (size_t)(n0 + row) * K + k0_ + cg * 8, &Bs[buf][lin * 8]); \
    } \
  } while (0)

  const int NT = KH >> 6;
  PSTAGE(0, 0);
  for (int t = 0; t < NT; ++t) {
    const int cur = t & 1;
    if (t + 1 < NT) {
      PSTAGE(cur ^ 1, t + 1);
      asm volatile("s_waitcnt vmcnt(8)" ::: "memory");
    } else {
      asm volatile("s_waitcnt vmcnt(0)" ::: "memory");
    }
    __builtin_amdgcn_sched_barrier(0);
    __builtin_amdgcn_s_barrier();
    __builtin_amdgcn_sched_barrier(0);
#pragma unroll
    for (int ks = 0; ks < 2; ++ks) {
      s16x8 af[4], bf[4];
#pragma unroll
      for (int mt = 0; mt < 4; mt++) {
        int row = wm * 64 + mt * 16 + li;
        int slot = (4 * ks + g) ^ (row & 7);
        af[mt] = *(const s16x8*)&As[cur][row * 64 + slot * 8];
      }
#pragma unroll
      for (int nt = 0; nt < 4; nt++) {
        int row = wn * 64 + nt * 16 + li;
        int slot = (4 * ks + g) ^ (row & 7);
        bf[nt] = *(const s16x8*)&Bs[cur][row * 64 + slot * 8];
      }
#pragma unroll
      for (int mt = 0; mt < 4; mt++)
#pragma unroll
        for (int nt = 0; nt < 4; nt++)
          acc[mt][nt] = mfma16(af[mt], bf[nt], acc[mt][nt]);
    }
    __builtin_amdgcn_sched_barrier(0);
    __builtin_amdgcn_s_barrier();
    __builtin_amdgcn_sched_barrier(0);
  }
#undef PSTAGE

  asm volatile("s_nop 7\n\ts_nop 7" :::);
#pragma unroll
  for (int mt = 0; mt < 4; mt++) {
    int mrow = m0 + wm * 64 + mt * 16 + 4 * g;
#pragma unroll
    for (int nt = 0; nt < 4; nt++) {
      int ncol = n0 + wn * 64 + nt * 16 + li;
#pragma unroll
      for (int r = 0; r < 4; r++) {
        int mr = mrow + r;
        Pp[(size_t)mr * N + ncol] = acc[mt][nt][r];
      }
    }
  }
}

// ---------------------------------------------------------------------------
// Split-bf16 projection GEMM v2 (R13-proven: single-buffered BK=64) +
// A2/C2 M-stacking (CA merge). v3 (BK=32 dbuf) regressed -16us — reverted.
// ---------------------------------------------------------------------------
__global__ __launch_bounds__(256, 2) void sgemm_k(
    const unsigned short* __restrict__ Ah, const unsigned short* __restrict__ Al,
    const unsigned short* __restrict__ A2h, const unsigned short* __restrict__ A2l,
    const unsigned short* __restrict__ Bh, const unsigned short* __restrict__ Bl,
    const float* __restrict__ bias,
    unsigned short* __restrict__ Cb, unsigned short* __restrict__ C2b,
    int Ms, int M, int N, int K, int lbx)
{
  __shared__ __align__(16) unsigned short AsH[128 * 64];
  __shared__ __align__(16) unsigned short AsL[128 * 64];
  __shared__ __align__(16) unsigned short BsH[128 * 64];
  __shared__ __align__(16) unsigned short BsL[128 * 64];

  const int nwg = gridDim.x;
  const int bid = blockIdx.x;
  const int swz = (bid & 7) * (nwg >> 3) + (bid >> 3);
  const int nbx_m1 = (1 << lbx) - 1;
  const int n0 = (swz & nbx_m1) * 128;
  int m0 = (swz >> lbx) * 128;

  const unsigned short* Ahp = Ah;
  const unsigned short* Alp = Al;
  unsigned short* Cp = Cb;
  if (m0 >= Ms) { Ahp = A2h; Alp = A2l; Cp = C2b; m0 -= Ms; }

  const int tid = threadIdx.x;
  const int lane = tid & 63;
  const int w = tid >> 6;
  const int wm = w >> 1, wn = w & 1;
  const int li = lane & 15, g = lane >> 4;

  f32x4 acc[4][4] = {};

  const int NT = K >> 6;
  for (int t = 0; t < NT; ++t) {
    __syncthreads();
#pragma unroll
    for (int i = 0; i < 4; i++) {
      int lin = i * 256 + tid; int row = lin >> 3;
      int cg = (lin & 7) ^ (row & 7);
      size_t offA = (size_t)(m0 + row) * K + t * 64 + cg * 8;
      size_t offB = (size_t)(n0 + row) * K + t * 64 + cg * 8;
      gld16(Ahp + offA, &AsH[lin * 8]);
      gld16(Alp + offA, &AsL[lin * 8]);
      gld16(Bh + offB, &BsH[lin * 8]);
      gld16(Bl + offB, &BsL[lin * 8]);
    }
    asm volatile("s_waitcnt vmcnt(0)" ::: "memory");
    __syncthreads();
#pragma unroll
    for (int ks = 0; ks < 2; ++ks) {
      s16x8 ah[4], al[4], bh[4], bl[4];
#pragma unroll
      for (int mt = 0; mt < 4; mt++) {
        int row = wm * 64 + mt * 16 + li;
        int slot = (4 * ks + g) ^ (row & 7);
        ah[mt] = *(const s16x8*)&AsH[row * 64 + slot * 8];
        al[mt] = *(const s16x8*)&AsL[row * 64 + slot * 8];
      }
#pragma unroll
      for (int nt = 0; nt < 4; nt++) {
        int row = wn * 64 + nt * 16 + li;
        int slot = (4 * ks + g) ^ (row & 7);
        bh[nt] = *(const s16x8*)&BsH[row * 64 + slot * 8];
        bl[nt] = *(const s16x8*)&BsL[row * 64 + slot * 8];
      }
#pragma unroll
      for (int mt = 0; mt < 4; mt++)
#pragma unroll
        for (int nt = 0; nt < 4; nt++) {
          acc[mt][nt] = mfma16(ah[mt], bh[nt], acc[mt][nt]);
          acc[mt][nt] = mfma16(ah[mt], bl[nt], acc[mt][nt]);
          acc[mt][nt] = mfma16(al[mt], bh[nt], acc[mt][nt]);
        }
    }
  }

  asm volatile("s_nop 7\n\ts_nop 7" :::);
#pragma unroll
  for (int mt = 0; mt < 4; mt++) {
    int mrow = m0 + wm * 64 + mt * 16 + 4 * g;
#pragma unroll
    for (int nt = 0; nt < 4; nt++) {
      int ncol = n0 + wn * 64 + nt * 16 + li;
      float bv = bias[ncol];
#pragma unroll
      for (int r = 0; r < 4; r++) {
        int mr = mrow + r;
        Cp[(size_t)mr * N + ncol] = f2bf(acc[mt][nt][r] + bv);
      }
    }
  }
}

// ---------------------------------------------------------------------------
// Fused weight pre-pass (block-range dispatch)
// ---------------------------------------------------------------------------
__device__ __forceinline__ void dev_tc(const float* __restrict__ W,
    unsigned short* __restrict__ WT, int K, int N, int bid, char* ldsu)
{
  unsigned short (*Ls)[65] = (unsigned short (*)[65])ldsu;
  int ntx = N >> 6;
  int ty = bid / ntx, tx = bid - ty * ntx;
  int r0 = ty << 6, c0 = tx << 6;
  int tid = threadIdx.x;
  int rl = tid >> 4, cl = (tid & 15) << 2;
#pragma unroll
  for (int rr = 0; rr < 4; rr++) {
    f32x4 v = *(const f32x4*)&W[(size_t)(r0 + rl + rr * 16) * N + c0 + cl];
#pragma unroll
    for (int j = 0; j < 4; j++) Ls[rl + rr * 16][cl + j] = f2bf(v[j]);
  }
  __syncthreads();
#pragma unroll
  for (int rr = 0; rr < 4; rr++) {
    int nl = rl + rr * 16;
    u16x4 o;
#pragma unroll
    for (int j = 0; j < 4; j++) o[j] = Ls[cl + j][nl];
    *(u16x4*)&WT[(size_t)(c0 + nl) * K + r0 + cl] = o;
  }
}

__device__ __forceinline__ void dev_tc2(const float* __restrict__ W,
    unsigned short* __restrict__ WTh, unsigned short* __restrict__ WTl,
    int K, int N, int bid, char* ldsu)
{
  float (*Ls)[65] = (float (*)[65])ldsu;
  int ntx = N >> 6;
  int ty = bid / ntx, tx = bid - ty * ntx;
  int r0 = ty << 6, c0 = tx << 6;
  int tid = threadIdx.x;
  int rl = tid >> 4, cl = (tid & 15) << 2;
#pragma unroll
  for (int rr = 0; rr < 4; rr++) {
    f32x4 v = *(const f32x4*)&W[(size_t)(r0 + rl + rr * 16) * N + c0 + cl];
#pragma unroll
    for (int j = 0; j < 4; j++) Ls[rl + rr * 16][cl + j] = v[j];
  }
  __syncthreads();
#pragma unroll
  for (int rr = 0; rr < 4; rr++) {
    int nl = rl + rr * 16;
    u16x4 oh, ol;
#pragma unroll
    for (int j = 0; j < 4; j++) {
      float v = Ls[cl + j][nl];
      unsigned short h = f2bf(v);
      oh[j] = h; ol[j] = f2bf(v - bf2f(h));
    }
    *(u16x4*)&WTh[(size_t)(c0 + nl) * K + r0 + cl] = oh;
    *(u16x4*)&WTl[(size_t)(c0 + nl) * K + r0 + cl] = ol;
  }
}

__global__ __launch_bounds__(256) void prep_w_k(
    const float* saWq, const float* caWq, const float* saWo, const float* caWo,
    const float* W1, const float* W2,
    unsigned short* WqTsaH, unsigned short* WqTsaL,
    unsigned short* WqTcaH, unsigned short* WqTcaL,
    unsigned short* WoTsa, unsigned short* WoTca,
    unsigned short* W1T, unsigned short* W2T)
{
  __shared__ __align__(16) char LDSU[64 * 65 * 4];
  int bid = blockIdx.x;
  if (bid < 256)       dev_tc2(saWq, WqTsaH, WqTsaL, 1024, 1024, bid, LDSU);
  else if (bid < 512)  dev_tc2(caWq, WqTcaH, WqTcaL, 1024, 1024, bid - 256, LDSU);
  else if (bid < 768)  dev_tc (saWo, WoTsa, 1024, 1024, bid - 512, LDSU);
  else if (bid < 1024) dev_tc (caWo, WoTca, 1024, 1024, bid - 768, LDSU);
  else if (bid < 2048) dev_tc (W1, W1T, 1024, 4096, bid - 1024, LDSU);
  else                 dev_tc (W2, W2T, 4096, 1024, bid - 2048, LDSU);
}

// ---------------------------------------------------------------------------
// Fused activation pre-pass
// ---------------------------------------------------------------------------
__device__ __forceinline__ void dev_cvt2row(const float* __restrict__ X,
    unsigned short* __restrict__ H, unsigned short* __restrict__ L, int bid)
{
  int i = (bid * 256 + threadIdx.x) * 4;
  f32x4 v = *(const f32x4*)&X[i];
  u16x4 hh, ll;
#pragma unroll
  for (int j = 0; j < 4; j++) {
    unsigned short h = f2bf(v[j]);
    hh[j] = h; ll[j] = f2bf(v[j] - bf2f(h));
  }
  *(u16x4*)&H[i] = hh;
  *(u16x4*)&L[i] = ll;
}

__device__ __forceinline__ void dev_wrel(const float* __restrict__ Wq,
    float* __restrict__ Wr, int bid)
{
  int idx = bid * 256 + threadIdx.x;
  int k = idx >> 4, h = idx & 15;
  const float* src = Wq + (size_t)k * 1024 + h * 64;
  float a = 0.f, s = 0.f;
#pragma unroll
  for (int d = 0; d < 64; d += 4) {
    f32x4 v = *(const f32x4*)&src[d];
#pragma unroll
    for (int j = 0; j < 4; j++) { a += v[j] * (float)(d + j + 1024); s += v[j]; }
  }
  Wr[k * 32 + h] = a;
  Wr[k * 32 + 16 + h] = s;
}

__device__ __forceinline__ void dev_crel(const float* __restrict__ bq,
    float* __restrict__ cr)
{
  int h = threadIdx.x;
  if (h < 16) {
    float a = 0.f, s = 0.f;
    for (int d = 0; d < 64; d++) { float v = bq[h * 64 + d]; a += v * (float)(d + 1024); s += v; }
    cr[h] = a; cr[16 + h] = s;
  }
}

__global__ __launch_bounds__(256) void prep_a_k(
    const float* tgt, const float* mem,
    unsigned short* tgth, unsigned short* tgtl,
    unsigned short* memh, unsigned short* meml,
    const float* saWq, const float* caWq, float* wrelsa, float* wrelca,
    const float* sabq, const float* cabq, float* crelsa, float* crelca)
{
  int bid = blockIdx.x;
  if (bid < 4096)       dev_cvt2row(tgt, tgth, tgtl, bid);
  else if (bid < 8192)  dev_cvt2row(mem, memh, meml, bid - 4096);
  else if (bid < 8256)  dev_wrel(saWq, wrelsa, bid - 8192);
  else if (bid < 8320)  dev_wrel(caWq, wrelca, bid - 8256);
  else if (bid == 8320) dev_crel(sabq, crelsa);
  else                  dev_crel(cabq, crelca);
}

// ---------------------------------------------------------------------------
// rel coefficients mini-GEMM (f32-exact): Out[4096][32] = X[4096][1024]@Wr + cr
// ---------------------------------------------------------------------------
__global__ __launch_bounds__(256) void relgemm_k(const float* __restrict__ X,
    const float* __restrict__ Wr, const float* __restrict__ cr,
    float* __restrict__ Out)
{
  __shared__ float Xs[8][256];
  __shared__ float Ws[256][32];
  int r0 = blockIdx.x * 8;
  int tid = threadIdx.x;
  int rl = tid >> 5, col = tid & 31;
  float acc = 0.f;
  for (int kc = 0; kc < 1024; kc += 256) {
    __syncthreads();
    {
      const float* xs = X + (size_t)(r0 + rl) * 1024 + kc + col * 8;
      *(f32x4*)&Xs[rl][col * 8] = *(const f32x4*)xs;
      *(f32x4*)&Xs[rl][col * 8 + 4] = *(const f32x4*)(xs + 4);
    }
    {
      const float* wsrc = Wr + (size_t)(kc + tid) * 32;
#pragma unroll
      for (int i = 0; i < 8; i++) *(f32x4*)&Ws[tid][i * 4] = *(const f32x4*)&wsrc[i * 4];
    }
    __syncthreads();
#pragma unroll 8
    for (int kk = 0; kk < 256; ++kk) acc += Xs[rl][kk] * Ws[kk][col];
  }
  Out[(size_t)(r0 + rl) * 32 + col] = acc + cr[col];
}

// ---------------------------------------------------------------------------
// Fused attention — R11-proven body VERBATIM. FROZEN.
// ---------------------------------------------------------------------------
template<bool CAUSAL>
__global__ __launch_bounds__(512) void attn_k(
    const unsigned short* __restrict__ Qb, const unsigned short* __restrict__ KVb,
    const float* __restrict__ rAS, unsigned short* __restrict__ Ob)
{
  const int bh = blockIdx.x;
  const int b = bh >> 4, h = bh & 15;
  const int y = blockIdx.y;               // 0..7
  const int tid = threadIdx.x, lane = tid & 63, w = tid >> 6;
  const int g = lane >> 4, li = lane & 15;

  __shared__ __align__(16) unsigned short Kt[64 * 64];   // [k][d] swizzled
  __shared__ __align__(16) unsigned short KT[64 * 64];   // [d][k] swizzled
  __shared__ __align__(16) unsigned short Pl[8][16 * 64];

  const int tile = CAUSAL ? ((w < 4) ? y : (15 - y)) : (2 * y + (w >> 2));
  const int q0 = tile * 64 + (w & 3) * 16;
  const int nkb = CAUSAL ? (16 - y) : 16;

  s16x8 qf[2];
  {
    const unsigned short* qrow = Qb + (size_t)(b * 1024 + q0 + li) * 1024 + h * 64;
    qf[0] = *(const s16x8*)&qrow[8 * g];
    qf[1] = *(const s16x8*)&qrow[8 * g + 32];
  }
  const float SCL2 = 0.125f * 1.44269504f;
  int qri[4];
  float C0c[4], C1c[4], rSc[4], rS1c[4];
#pragma unroll
  for (int r = 0; r < 4; r++) {
    int qr = q0 + 4 * g + r;
    qri[r] = qr;
    float rA = rAS[(size_t)(b * 1024 + qr) * 32 + h];
    float rS = rAS[(size_t)(b * 1024 + qr) * 32 + 16 + h];
    int q1 = (qr + 1 < 1024) ? qr + 1 : 1023;
    float rA1 = rAS[(size_t)(b * 1024 + q1) * 32 + h];
    float rS1 = rAS[(size_t)(b * 1024 + q1) * 32 + 16 + h];
    C0c[r]  = (rA + (float)(qr - 1023) * rS) * SCL2;
    rSc[r]  = rS * SCL2;
    C1c[r]  = (rA1 + (float)(qr + 2) * rS1) * SCL2;
    rS1c[r] = rS1 * SCL2;
  }

  float mrow[4], lrow[4];
#pragma unroll
  for (int r = 0; r < 4; r++) { mrow[r] = -3.0e38f; lrow[r] = 0.f; }
  f32x4 accO[4] = {};

  for (int kbk = 0; kbk < nkb; kbk++) {
    __syncthreads();
    // ---- stage K[k][d] + KT[d][k]: krow = lane, dcols = w*8..w*8+7 ----
    {
      const unsigned short* src = KVb + (size_t)(b * 1024 + kbk * 64 + lane) * 1024 + h * 64 + w * 8;
      s16x8 v = *(const s16x8*)src;
      int slot = w ^ (lane & 7);
      *(s16x8*)&Kt[lane * 64 + slot * 8] = v;
#pragma unroll
      for (int j = 0; j < 8; j++) {
        int d = w * 8 + j;
        KT[d * 64 + (((lane >> 3) ^ (d & 7)) * 8) + (lane & 7)] = (unsigned short)v[j];
      }
    }
    __syncthreads();
    if (!CAUSAL || kbk <= tile) {
      const bool diag = CAUSAL && (kbk == tile);
      // S = Q K^T
      f32x4 accS[4];
#pragma unroll
      for (int nt = 0; nt < 4; nt++) {
        int krow = li + 16 * nt;
        f32x4 c = {};
#pragma unroll
        for (int ks = 0; ks < 2; ks++) {
          int slot = (g + 4 * ks) ^ (krow & 7);
          s16x8 kf = *(const s16x8*)&Kt[krow * 64 + slot * 8];
          c = mfma16(qf[ks], kf, c);
        }
        accS[nt] = c;
      }
      // skew + (diag) mask + online softmax (log2 domain)
      float pv[4][4];
      float bm[4];
#pragma unroll
      for (int r = 0; r < 4; r++) bm[r] = -3.0e38f;
#pragma unroll
      for (int nt = 0; nt < 4; nt++) {
        int kk = kbk * 64 + 16 * nt + li;
        float kkf = (float)kk;
#pragma unroll
        for (int r = 0; r < 4; r++) {
          float sk = (kk <= qri[r]) ? fmaf(kkf, -rSc[r], C0c[r])
                   : ((kk == qri[r] + 1) ? 0.f : fmaf(kkf, -rS1c[r], C1c[r]));
          float lg = fmaf(accS[nt][r], SCL2, sk);
          if (diag && kk > qri[r]) lg = -1.0e9f;
          pv[nt][r] = lg;
          bm[r] = fmaxf(bm[r], lg);
        }
      }
#pragma unroll
      for (int off = 1; off < 16; off <<= 1)
#pragma unroll
        for (int r = 0; r < 4; r++)
          bm[r] = fmaxf(bm[r], __shfl_xor(bm[r], off, 64));
      float scl[4], rsum[4];
#pragma unroll
      for (int r = 0; r < 4; r++) {
        float mnew = fmaxf(mrow[r], bm[r]);
        scl[r] = exp2f(mrow[r] - mnew);
        mrow[r] = mnew;
        rsum[r] = 0.f;
      }
#pragma unroll
      for (int nt = 0; nt < 4; nt++)
#pragma unroll
        for (int r = 0; r < 4; r++) {
          float p = exp2f(pv[nt][r] - mrow[r]);
          pv[nt][r] = p;
          rsum[r] += p;
        }
#pragma unroll
      for (int off = 1; off < 16; off <<= 1)
#pragma unroll
        for (int r = 0; r < 4; r++)
          rsum[r] += __shfl_xor(rsum[r], off, 64);
#pragma unroll
      for (int r = 0; r < 4; r++) lrow[r] = lrow[r] * scl[r] + rsum[r];
      // write P (bf16) to per-wave LDS
#pragma unroll
      for (int nt = 0; nt < 4; nt++)
#pragma unroll
        for (int r = 0; r < 4; r++) {
          int qq = 4 * g + r;
          int kkk = 16 * nt + li;
          int slot = (kkk >> 3) ^ (qq & 7);
          Pl[w][qq * 64 + slot * 8 + (kkk & 7)] = f2bf(pv[nt][r]);
        }
      // rescale O
#pragma unroll
      for (int dt = 0; dt < 4; dt++)
#pragma unroll
        for (int r = 0; r < 4; r++) accO[dt][r] *= scl[r];
      // P fragments (per-wave LDS; same-wave RAW ordering in DS pipe)
      s16x8 pfk[2];
#pragma unroll
      for (int ks = 0; ks < 2; ks++) {
        int slotA = (g + 4 * ks) ^ (li & 7);
        pfk[ks] = *(const s16x8*)&Pl[w][li * 64 + slotA * 8];
      }
      // O += P @ V  (V == K; B-frag from KT[d][k])
#pragma unroll
      for (int dt = 0; dt < 4; dt++) {
#pragma unroll
        for (int ks = 0; ks < 2; ks++) {
          int drow = li + 16 * dt;
          int slotB = (g + 4 * ks) ^ (drow & 7);
          s16x8 vf = *(const s16x8*)&KT[drow * 64 + slotB * 8];
          accO[dt] = mfma16(pfk[ks], vf, accO[dt]);
        }
      }
    }
  }
  // epilogue: O / l -> bf16
  asm volatile("s_nop 7\n\ts_nop 7" :::);
#pragma unroll
  for (int dt = 0; dt < 4; dt++) {
    int dcol = h * 64 + li + 16 * dt;
#pragma unroll
    for (int r = 0; r < 4; r++) {
      int q = q0 + 4 * g + r;
      Ob[(size_t)(b * 1024 + q) * 1024 + dcol] = f2bf(accO[dt][r] / lrow[r]);
    }
  }
}

// ---------------------------------------------------------------------------
// LayerNorm rows of 1024; writes f32 and optional bf16 hi (+ optional lo).
// ---------------------------------------------------------------------------
__global__ __launch_bounds__(256) void ln_k(const float* __restrict__ X,
    const float* __restrict__ gw, const float* __restrict__ bw,
    float* __restrict__ O, unsigned short* __restrict__ Obh,
    unsigned short* __restrict__ Obl)
{
  int row = blockIdx.x;
  const float* x = X + (size_t)row * 1024;
  int tid = threadIdx.x;
  f32x4 v = *(const f32x4*)&x[tid * 4];
  float s = v[0] + v[1] + v[2] + v[3];
  float s2 = v[0]*v[0] + v[1]*v[1] + v[2]*v[2] + v[3]*v[3];
#pragma unroll
  for (int off = 32; off > 0; off >>= 1) {
    s += __shfl_down(s, off, 64);
    s2 += __shfl_down(s2, off, 64);
  }
  __shared__ float rb[8];
  if ((tid & 63) == 0) { rb[tid >> 6] = s; rb[4 + (tid >> 6)] = s2; }
  __syncthreads();
  float S = rb[0] + rb[1] + rb[2] + rb[3];
  float S2 = rb[4] + rb[5] + rb[6] + rb[7];
  float mu = S * (1.f / 1024.f);
  float var = S2 * (1.f / 1024.f) - mu * mu;
  float rstd = rsqrtf(var + 1e-5f);
  f32x4 go = *(const f32x4*)&gw[tid * 4];
  f32x4 bo = *(const f32x4*)&bw[tid * 4];
  f32x4 r;
#pragma unroll
  for (int j = 0; j < 4; j++) r[j] = (v[j] - mu) * rstd * go[j] + bo[j];
  *(f32x4*)&O[(size_t)row * 1024 + tid * 4] = r;
  if (Obh) {
    u16x4 oh;
#pragma unroll
    for (int j = 0; j < 4; j++) oh[j] = f2bf(r[j]);
    *(u16x4*)&Obh[(size_t)row * 1024 + tid * 4] = oh;
    if (Obl) {
      u16x4 ol;
#pragma unroll
      for (int j = 0; j < 4; j++) ol[j] = f2bf(r[j] - bf2f(f2bf(r[j])));
      *(u16x4*)&Obl[(size_t)row * 1024 + tid * 4] = ol;
    }
  }
}

// ---------------------------------------------------------------------------
// Fused FFN2 reduce + LN3: x = P0 + P1 + b2 + resid; out = LN(x).
// ---------------------------------------------------------------------------
__global__ __launch_bounds__(256) void redln_k(
    const float* __restrict__ P0, const float* __restrict__ P1,
    const float* __restrict__ bias, const float* __restrict__ resid,
    const float* __restrict__ gw, const float* __restrict__ bw,
    float* __restrict__ O)
{
  int row = blockIdx.x;
  int tid = threadIdx.x;
  size_t base = (size_t)row * 1024 + tid * 4;
  f32x4 a = *(const f32x4*)&P0[base];
  f32x4 b = *(const f32x4*)&P1[base];
  f32x4 c = *(const f32x4*)&resid[base];
  f32x4 bv = *(const f32x4*)&bias[tid * 4];
  f32x4 v;
#pragma unroll
  for (int j = 0; j < 4; j++) v[j] = a[j] + b[j] + bv[j] + c[j];
  float s = v[0] + v[1] + v[2] + v[3];
  float s2 = v[0]*v[0] + v[1]*v[1] + v[2]*v[2] + v[3]*v[3];
#pragma unroll
  for (int off = 32; off > 0; off >>= 1) {
    s += __shfl_down(s, off, 64);
    s2 += __shfl_down(s2, off, 64);
  }
  __shared__ float rb[8];
  if ((tid & 63) == 0) { rb[tid >> 6] = s; rb[4 + (tid >> 6)] = s2; }
  __syncthreads();
  float S = rb[0] + rb[1] + rb[2] + rb[3];
  float S2 = rb[4] + rb[5] + rb[6] + rb[7];
  float mu = S * (1.f / 1024.f);
  float var = S2 * (1.f / 1024.f) - mu * mu;
  float rstd = rsqrtf(var + 1e-5f);
  f32x4 go = *(const f32x4*)&gw[tid * 4];
  f32x4 bo = *(const f32x4*)&bw[tid * 4];
  f32x4 r;
#pragma unroll
  for (int j = 0; j < 4; j++) r[j] = (v[j] - mu) * rstd * go[j] + bo[j];
  *(f32x4*)&O[base] = r;
}

// ---------------------------------------------------------------------------
extern "C" void kernel_launch(void* const* d_in, const int* in_sizes, int n_in,
                              void* d_out, int out_size, void* d_ws, size_t ws_size,
                              hipStream_t stream)
{
  const float* tgt  = (const float*)d_in[0];
  const float* mem  = (const float*)d_in[1];
  const float* saWq = (const float*)d_in[3];
  const float* sabq = (const float*)d_in[4];
  const float* saWo = (const float*)d_in[5];
  const float* sabo = (const float*)d_in[6];
  const float* caWq = (const float*)d_in[7];
  const float* cabq = (const float*)d_in[8];
  const float* caWo = (const float*)d_in[9];
  const float* cabo = (const float*)d_in[10];
  const float* W1   = (const float*)d_in[11];
  const float* b1   = (const float*)d_in[12];
  const float* W2   = (const float*)d_in[13];
  const float* b2   = (const float*)d_in[14];
  const float* g1   = (const float*)d_in[15];
  const float* be1  = (const float*)d_in[16];
  const float* g2   = (const float*)d_in[17];
  const float* be2  = (const float*)d_in[18];
  const float* g3   = (const float*)d_in[19];
  const float* be3  = (const float*)d_in[20];
  float* out = (float*)d_out;

  char* ws = (char*)d_ws;
  const size_t ACT = (size_t)4096 * 1024;
  unsigned short* RA   = (unsigned short*)ws; ws += ACT * 2;  // tgth -> attnb(SA) -> x1h -> attnb(CA) -> P1(lo half)
  unsigned short* RB   = (unsigned short*)ws; ws += ACT * 2;  // tgtl -> x1l -> P1(hi half)
  unsigned short* qkvb = (unsigned short*)ws; ws += ACT * 2;  // SA qkv -> CA q -> P0(lo half)
  unsigned short* kvb  = (unsigned short*)ws; ws += ACT * 2;  // CA kv -> P0(hi half)
  unsigned short* x2b  = (unsigned short*)ws; ws += ACT * 2;
  unsigned short* RF   = (unsigned short*)ws; ws += (size_t)4096 * 4096 * 2; // memh+meml -> hb
  unsigned short* memh = RF;
  unsigned short* meml = RF + ACT;
  unsigned short* hb   = RF;
  float* P0 = (float*)qkvb;   // 16 MB spanning qkvb+kvb (dead after CA attn)
  float* P1 = (float*)RA;     // 16 MB spanning RA+RB  (dead after CA-out bgemm)
  unsigned short* WqTsaH = (unsigned short*)ws; ws += (size_t)1024 * 1024 * 2;
  unsigned short* WqTsaL = (unsigned short*)ws; ws += (size_t)1024 * 1024 * 2;
  unsigned short* WoTsa  = (unsigned short*)ws; ws += (size_t)1024 * 1024 * 2;
  unsigned short* WqTcaH = (unsigned short*)ws; ws += (size_t)1024 * 1024 * 2;
  unsigned short* WqTcaL = (unsigned short*)ws; ws += (size_t)1024 * 1024 * 2;
  unsigned short* WoTca  = (unsigned short*)ws; ws += (size_t)1024 * 1024 * 2;
  unsigned short* W1T = (unsigned short*)ws; ws += (size_t)4096 * 1024 * 2;
  unsigned short* W2T = (unsigned short*)ws; ws += (size_t)4096 * 1024 * 2;
  float* x2f = (float*)ws; ws += (size_t)4096 * 1024 * 4;
  float* rAS = (float*)ws; ws += (size_t)4096 * 32 * 4;
  float* wrelsa = (float*)ws; ws += (size_t)1024 * 32 * 4;
  float* wrelca = (float*)ws; ws += (size_t)1024 * 32 * 4;
  float* crelsa = (float*)ws; ws += 128;
  float* crelca = (float*)ws; ws += 128;
  float* x1f = out;   // d_out doubles as x1 f32 scratch

  dim3 blk(256);

  // ---------------- fused pre-pass (2 launches) ----------------
  prep_w_k<<<dim3(3072), blk, 0, stream>>>(saWq, caWq, saWo, caWo, W1, W2,
      WqTsaH, WqTsaL, WqTcaH, WqTcaL, WoTsa, WoTca, W1T, W2T);
  prep_a_k<<<dim3(8322), blk, 0, stream>>>(tgt, mem, RA, RB, memh, meml,
      saWq, caWq, wrelsa, wrelca, sabq, cabq, crelsa, crelca);

  // ---------------- main pipeline ----------------
  sgemm_k<<<dim3(256), blk, 0, stream>>>(RA, RB, RA, RB, WqTsaH, WqTsaL, sabq,
      qkvb, qkvb, 1 << 30, 4096, 1024, 1024, 3);
  relgemm_k<<<dim3(512), blk, 0, stream>>>(tgt, wrelsa, crelsa, rAS);
  attn_k<true><<<dim3(64, 8), dim3(512), 0, stream>>>(qkvb, qkvb, rAS, RA);   // attnb = RA
  bgemm_k<false, true, false><<<dim3(256), blk, 0, stream>>>(RA, WoTsa, sabo, tgt, x1f, 4096, 1024, 1024, 3);
  ln_k<<<dim3(4096), blk, 0, stream>>>(x1f, g1, be1, x1f, RA, RB);            // x1h = RA, x1l = RB
  // CA projections merged: q (rows 0..4095, A=x1) + kv (rows 4096.., A=mem)
  sgemm_k<<<dim3(512), blk, 0, stream>>>(RA, RB, memh, meml, WqTcaH, WqTcaL, cabq,
      qkvb, kvb, 4096, 8192, 1024, 1024, 3);
  relgemm_k<<<dim3(512), blk, 0, stream>>>(x1f, wrelca, crelca, rAS);
  attn_k<false><<<dim3(64, 8), dim3(512), 0, stream>>>(qkvb, kvb, rAS, RA);   // attnb = RA
  bgemm_k<false, true, false><<<dim3(256), blk, 0, stream>>>(RA, WoTca, cabo, x1f, x2f, 4096, 1024, 1024, 3);
  ln_k<<<dim3(4096), blk, 0, stream>>>(x2f, g2, be2, x2f, x2b, nullptr);
  // FFN1 (hb overwrites memh/meml region — dead after CA kv projection)
  bgemm_k<true, false, true><<<dim3(1024), blk, 0, stream>>>(x2b, W1T, b1, nullptr, hb, 4096, 4096, 1024, 5);
  // FFN2 split-K x2 (P0 <- qkvb/kvb region, P1 <- RA/RB region; both dead)
  bgemm_pk<<<dim3(512), blk, 0, stream>>>(hb, W2T, P0, P1, 4096, 1024, 4096, 2048, 3);
  // fused reduce + LN3 -> out
  redln_k<<<dim3(4096), blk, 0, stream>>>(P0, P1, b2, x2f, g3, be3, out);

  (void)in_sizes; (void)n_in; (void)out_size; (void)ws_size;
}

// Round 16
// 453.387 us; speedup vs baseline: 1.0965x; 1.0128x over previous
//
#include <hip/hip_runtime.h>

typedef __attribute__((ext_vector_type(4))) float f32x4;
typedef __attribute__((ext_vector_type(8))) short s16x8;
typedef __attribute__((ext_vector_type(4))) unsigned short u16x4;

__device__ __forceinline__ unsigned short f2bf(float x) {
  union { float f; unsigned u; } un; un.f = x;
  unsigned u = un.u;
  u += 0x7FFFu + ((u >> 16) & 1u);
  return (unsigned short)(u >> 16);
}
__device__ __forceinline__ float bf2f(unsigned short h) {
  union { unsigned u; float f; } un; un.u = ((unsigned)h) << 16; return un.f;
}

// Canonical accumulate form: D tied to C ("+v").
__device__ __forceinline__ f32x4 mfma16(s16x8 a, s16x8 b, f32x4 c) {
  asm("v_mfma_f32_16x16x32_bf16 %0, %1, %2, %0" : "+v"(c) : "v"(a), "v"(b));
  return c;
}

__device__ __forceinline__ void gld16(const void* g, void* l) {
  __builtin_amdgcn_global_load_lds(
      (const __attribute__((address_space(1))) void*)g,
      (__attribute__((address_space(3))) void*)l, 16, 0, 0);
}

// ---------------------------------------------------------------------------
// bf16 GEMM, m97-style (R11-proven, unchanged) — used for FFN1.
// ---------------------------------------------------------------------------
template<bool RELU, bool RESID, bool OUT_BF16>
__global__ __launch_bounds__(256, 2) void bgemm_k(
    const unsigned short* __restrict__ Ab, const unsigned short* __restrict__ Bb,
    const float* __restrict__ bias, const float* __restrict__ resid,
    void* __restrict__ Cp, int M, int N, int K, int lbx)
{
  __shared__ __align__(16) unsigned short As[2][128 * 64];
  __shared__ __align__(16) unsigned short Bs[2][128 * 64];

  const int nwg = gridDim.x;
  const int bid = blockIdx.x;
  const int swz = (bid & 7) * (nwg >> 3) + (bid >> 3);
  const int nbx_m1 = (1 << lbx) - 1;
  const int n0 = (swz & nbx_m1) * 128;
  const int m0 = (swz >> lbx) * 128;

  const int tid = threadIdx.x;
  const int lane = tid & 63;
  const int w = tid >> 6;
  const int wm = w >> 1, wn = w & 1;
  const int li = lane & 15, g = lane >> 4;

  f32x4 acc[4][4] = {};

#define STAGE(buf, kt) do { \
    const int k0_ = (kt) * 64; \
    _Pragma("unroll") \
    for (int i_ = 0; i_ < 4; i_++) { \
      int lin = i_ * 256 + tid; int row = lin >> 3; \
      int cg = (lin & 7) ^ (row & 7); \
      gld16(Ab + (size_t)(m0 + row) * K + k0_ + cg * 8, &As[buf][lin * 8]); \
    } \
    _Pragma("unroll") \
    for (int i_ = 0; i_ < 4; i_++) { \
      int lin = i_ * 256 + tid; int row = lin >> 3; \
      int cg = (lin & 7) ^ (row & 7); \
      gld16(Bb + (size_t)(n0 + row) * K + k0_ + cg * 8, &Bs[buf][lin * 8]); \
    } \
  } while (0)

  const int NT = K >> 6;
  STAGE(0, 0);
  for (int t = 0; t < NT; ++t) {
    const int cur = t & 1;
    if (t + 1 < NT) {
      STAGE(cur ^ 1, t + 1);
      asm volatile("s_waitcnt vmcnt(8)" ::: "memory");
    } else {
      asm volatile("s_waitcnt vmcnt(0)" ::: "memory");
    }
    __builtin_amdgcn_sched_barrier(0);
    __builtin_amdgcn_s_barrier();
    __builtin_amdgcn_sched_barrier(0);
#pragma unroll
    for (int ks = 0; ks < 2; ++ks) {
      s16x8 af[4], bf[4];
#pragma unroll
      for (int mt = 0; mt < 4; mt++) {
        int row = wm * 64 + mt * 16 + li;
        int slot = (4 * ks + g) ^ (row & 7);
        af[mt] = *(const s16x8*)&As[cur][row * 64 + slot * 8];
      }
#pragma unroll
      for (int nt = 0; nt < 4; nt++) {
        int row = wn * 64 + nt * 16 + li;
        int slot = (4 * ks + g) ^ (row & 7);
        bf[nt] = *(const s16x8*)&Bs[cur][row * 64 + slot * 8];
      }
#pragma unroll
      for (int mt = 0; mt < 4; mt++)
#pragma unroll
        for (int nt = 0; nt < 4; nt++)
          acc[mt][nt] = mfma16(af[mt], bf[nt], acc[mt][nt]);
    }
    __builtin_amdgcn_sched_barrier(0);
    __builtin_amdgcn_s_barrier();
    __builtin_amdgcn_sched_barrier(0);
  }
#undef STAGE

  asm volatile("s_nop 7\n\ts_nop 7" :::);
#pragma unroll
  for (int mt = 0; mt < 4; mt++) {
    int mrow = m0 + wm * 64 + mt * 16 + 4 * g;
#pragma unroll
    for (int nt = 0; nt < 4; nt++) {
      int ncol = n0 + wn * 64 + nt * 16 + li;
      float bv = bias ? bias[ncol] : 0.f;
#pragma unroll
      for (int r = 0; r < 4; r++) {
        int mr = mrow + r;
        float v = acc[mt][nt][r] + bv;
        if (RESID) v += resid[(size_t)mr * N + ncol];
        if (RELU) v = fmaxf(v, 0.f);
        if (OUT_BF16) ((unsigned short*)Cp)[(size_t)mr * N + ncol] = f2bf(v);
        else          ((float*)Cp)[(size_t)mr * N + ncol] = v;
      }
    }
  }
}

// ---------------------------------------------------------------------------
// Split-K bgemm (R15-proven): blocks with m-tile >= M/128 handle K-range
// [KH,2*KH) and write partial P1; else [0,KH) -> P0. f32 partials.
// ---------------------------------------------------------------------------
__global__ __launch_bounds__(256, 2) void bgemm_pk(
    const unsigned short* __restrict__ Ab, const unsigned short* __restrict__ Bb,
    float* __restrict__ P0, float* __restrict__ P1,
    int M, int N, int K, int KH, int lbx)
{
  __shared__ __align__(16) unsigned short As[2][128 * 64];
  __shared__ __align__(16) unsigned short Bs[2][128 * 64];

  const int nwg = gridDim.x;
  const int bid = blockIdx.x;
  const int swz = (bid & 7) * (nwg >> 3) + (bid >> 3);
  const int nbx_m1 = (1 << lbx) - 1;
  const int n0 = (swz & nbx_m1) * 128;
  int m0 = (swz >> lbx) * 128;

  int kb = 0;
  float* Pp = P0;
  if (m0 >= M) { m0 -= M; kb = KH; Pp = P1; }

  const int tid = threadIdx.x;
  const int lane = tid & 63;
  const int w = tid >> 6;
  const int wm = w >> 1, wn = w & 1;
  const int li = lane & 15, g = lane >> 4;

  f32x4 acc[4][4] = {};

#define PSTAGE(buf, kt) do { \
    const int k0_ = kb + (kt) * 64; \
    _Pragma("unroll") \
    for (int i_ = 0; i_ < 4; i_++) { \
      int lin = i_ * 256 + tid; int row = lin >> 3; \
      int cg = (lin & 7) ^ (row & 7); \
      gld16(Ab + (size_t)(m0 + row) * K + k0_ + cg * 8, &As[buf][lin * 8]); \
    } \
    _Pragma("unroll") \
    for (int i_ = 0; i_ < 4; i_++) { \
      int lin = i_ * 256 + tid; int row = lin >> 3; \
      int cg = (lin & 7) ^ (row & 7); \
      gld16(Bb + (size_t)(n0 + row) * K + k0_ + cg * 8, &Bs[buf][lin * 8]); \
    } \
  } while (0)

  const int NT = KH >> 6;
  PSTAGE(0, 0);
  for (int t = 0; t < NT; ++t) {
    const int cur = t & 1;
    if (t + 1 < NT) {
      PSTAGE(cur ^ 1, t + 1);
      asm volatile("s_waitcnt vmcnt(8)" ::: "memory");
    } else {
      asm volatile("s_waitcnt vmcnt(0)" ::: "memory");
    }
    __builtin_amdgcn_sched_barrier(0);
    __builtin_amdgcn_s_barrier();
    __builtin_amdgcn_sched_barrier(0);
#pragma unroll
    for (int ks = 0; ks < 2; ++ks) {
      s16x8 af[4], bf[4];
#pragma unroll
      for (int mt = 0; mt < 4; mt++) {
        int row = wm * 64 + mt * 16 + li;
        int slot = (4 * ks + g) ^ (row & 7);
        af[mt] = *(const s16x8*)&As[cur][row * 64 + slot * 8];
      }
#pragma unroll
      for (int nt = 0; nt < 4; nt++) {
        int row = wn * 64 + nt * 16 + li;
        int slot = (4 * ks + g) ^ (row & 7);
        bf[nt] = *(const s16x8*)&Bs[cur][row * 64 + slot * 8];
      }
#pragma unroll
      for (int mt = 0; mt < 4; mt++)
#pragma unroll
        for (int nt = 0; nt < 4; nt++)
          acc[mt][nt] = mfma16(af[mt], bf[nt], acc[mt][nt]);
    }
    __builtin_amdgcn_sched_barrier(0);
    __builtin_amdgcn_s_barrier();
    __builtin_amdgcn_sched_barrier(0);
  }
#undef PSTAGE

  asm volatile("s_nop 7\n\ts_nop 7" :::);
#pragma unroll
  for (int mt = 0; mt < 4; mt++) {
    int mrow = m0 + wm * 64 + mt * 16 + 4 * g;
#pragma unroll
    for (int nt = 0; nt < 4; nt++) {
      int ncol = n0 + wn * 64 + nt * 16 + li;
#pragma unroll
      for (int r = 0; r < 4; r++) {
        int mr = mrow + r;
        Pp[(size_t)mr * N + ncol] = acc[mt][nt][r];
      }
    }
  }
}

// ---------------------------------------------------------------------------
// Split-bf16 projection GEMM v2 (R13-proven) + A2/C2 M-stacking (CA merge).
// ---------------------------------------------------------------------------
__global__ __launch_bounds__(256, 2) void sgemm_k(
    const unsigned short* __restrict__ Ah, const unsigned short* __restrict__ Al,
    const unsigned short* __restrict__ A2h, const unsigned short* __restrict__ A2l,
    const unsigned short* __restrict__ Bh, const unsigned short* __restrict__ Bl,
    const float* __restrict__ bias,
    unsigned short* __restrict__ Cb, unsigned short* __restrict__ C2b,
    int Ms, int M, int N, int K, int lbx)
{
  __shared__ __align__(16) unsigned short AsH[128 * 64];
  __shared__ __align__(16) unsigned short AsL[128 * 64];
  __shared__ __align__(16) unsigned short BsH[128 * 64];
  __shared__ __align__(16) unsigned short BsL[128 * 64];

  const int nwg = gridDim.x;
  const int bid = blockIdx.x;
  const int swz = (bid & 7) * (nwg >> 3) + (bid >> 3);
  const int nbx_m1 = (1 << lbx) - 1;
  const int n0 = (swz & nbx_m1) * 128;
  int m0 = (swz >> lbx) * 128;

  const unsigned short* Ahp = Ah;
  const unsigned short* Alp = Al;
  unsigned short* Cp = Cb;
  if (m0 >= Ms) { Ahp = A2h; Alp = A2l; Cp = C2b; m0 -= Ms; }

  const int tid = threadIdx.x;
  const int lane = tid & 63;
  const int w = tid >> 6;
  const int wm = w >> 1, wn = w & 1;
  const int li = lane & 15, g = lane >> 4;

  f32x4 acc[4][4] = {};

  const int NT = K >> 6;
  for (int t = 0; t < NT; ++t) {
    __syncthreads();
#pragma unroll
    for (int i = 0; i < 4; i++) {
      int lin = i * 256 + tid; int row = lin >> 3;
      int cg = (lin & 7) ^ (row & 7);
      size_t offA = (size_t)(m0 + row) * K + t * 64 + cg * 8;
      size_t offB = (size_t)(n0 + row) * K + t * 64 + cg * 8;
      gld16(Ahp + offA, &AsH[lin * 8]);
      gld16(Alp + offA, &AsL[lin * 8]);
      gld16(Bh + offB, &BsH[lin * 8]);
      gld16(Bl + offB, &BsL[lin * 8]);
    }
    asm volatile("s_waitcnt vmcnt(0)" ::: "memory");
    __syncthreads();
#pragma unroll
    for (int ks = 0; ks < 2; ++ks) {
      s16x8 ah[4], al[4], bh[4], bl[4];
#pragma unroll
      for (int mt = 0; mt < 4; mt++) {
        int row = wm * 64 + mt * 16 + li;
        int slot = (4 * ks + g) ^ (row & 7);
        ah[mt] = *(const s16x8*)&AsH[row * 64 + slot * 8];
        al[mt] = *(const s16x8*)&AsL[row * 64 + slot * 8];
      }
#pragma unroll
      for (int nt = 0; nt < 4; nt++) {
        int row = wn * 64 + nt * 16 + li;
        int slot = (4 * ks + g) ^ (row & 7);
        bh[nt] = *(const s16x8*)&BsH[row * 64 + slot * 8];
        bl[nt] = *(const s16x8*)&BsL[row * 64 + slot * 8];
      }
#pragma unroll
      for (int mt = 0; mt < 4; mt++)
#pragma unroll
        for (int nt = 0; nt < 4; nt++) {
          acc[mt][nt] = mfma16(ah[mt], bh[nt], acc[mt][nt]);
          acc[mt][nt] = mfma16(ah[mt], bl[nt], acc[mt][nt]);
          acc[mt][nt] = mfma16(al[mt], bh[nt], acc[mt][nt]);
        }
    }
  }

  asm volatile("s_nop 7\n\ts_nop 7" :::);
#pragma unroll
  for (int mt = 0; mt < 4; mt++) {
    int mrow = m0 + wm * 64 + mt * 16 + 4 * g;
#pragma unroll
    for (int nt = 0; nt < 4; nt++) {
      int ncol = n0 + wn * 64 + nt * 16 + li;
      float bv = bias[ncol];
#pragma unroll
      for (int r = 0; r < 4; r++) {
        int mr = mrow + r;
        Cp[(size_t)mr * N + ncol] = f2bf(acc[mt][nt][r] + bv);
      }
    }
  }
}

// ---------------------------------------------------------------------------
// Fused weight pre-pass (block-range dispatch)
// ---------------------------------------------------------------------------
__device__ __forceinline__ void dev_tc(const float* __restrict__ W,
    unsigned short* __restrict__ WT, int K, int N, int bid, char* ldsu)
{
  unsigned short (*Ls)[65] = (unsigned short (*)[65])ldsu;
  int ntx = N >> 6;
  int ty = bid / ntx, tx = bid - ty * ntx;
  int r0 = ty << 6, c0 = tx << 6;
  int tid = threadIdx.x;
  int rl = tid >> 4, cl = (tid & 15) << 2;
#pragma unroll
  for (int rr = 0; rr < 4; rr++) {
    f32x4 v = *(const f32x4*)&W[(size_t)(r0 + rl + rr * 16) * N + c0 + cl];
#pragma unroll
    for (int j = 0; j < 4; j++) Ls[rl + rr * 16][cl + j] = f2bf(v[j]);
  }
  __syncthreads();
#pragma unroll
  for (int rr = 0; rr < 4; rr++) {
    int nl = rl + rr * 16;
    u16x4 o;
#pragma unroll
    for (int j = 0; j < 4; j++) o[j] = Ls[cl + j][nl];
    *(u16x4*)&WT[(size_t)(c0 + nl) * K + r0 + cl] = o;
  }
}

__device__ __forceinline__ void dev_tc2(const float* __restrict__ W,
    unsigned short* __restrict__ WTh, unsigned short* __restrict__ WTl,
    int K, int N, int bid, char* ldsu)
{
  float (*Ls)[65] = (float (*)[65])ldsu;
  int ntx = N >> 6;
  int ty = bid / ntx, tx = bid - ty * ntx;
  int r0 = ty << 6, c0 = tx << 6;
  int tid = threadIdx.x;
  int rl = tid >> 4, cl = (tid & 15) << 2;
#pragma unroll
  for (int rr = 0; rr < 4; rr++) {
    f32x4 v = *(const f32x4*)&W[(size_t)(r0 + rl + rr * 16) * N + c0 + cl];
#pragma unroll
    for (int j = 0; j < 4; j++) Ls[rl + rr * 16][cl + j] = v[j];
  }
  __syncthreads();
#pragma unroll
  for (int rr = 0; rr < 4; rr++) {
    int nl = rl + rr * 16;
    u16x4 oh, ol;
#pragma unroll
    for (int j = 0; j < 4; j++) {
      float v = Ls[cl + j][nl];
      unsigned short h = f2bf(v);
      oh[j] = h; ol[j] = f2bf(v - bf2f(h));
    }
    *(u16x4*)&WTh[(size_t)(c0 + nl) * K + r0 + cl] = oh;
    *(u16x4*)&WTl[(size_t)(c0 + nl) * K + r0 + cl] = ol;
  }
}

__global__ __launch_bounds__(256) void prep_w_k(
    const float* saWq, const float* caWq, const float* saWo, const float* caWo,
    const float* W1, const float* W2,
    unsigned short* WqTsaH, unsigned short* WqTsaL,
    unsigned short* WqTcaH, unsigned short* WqTcaL,
    unsigned short* WoTsa, unsigned short* WoTca,
    unsigned short* W1T, unsigned short* W2T)
{
  __shared__ __align__(16) char LDSU[64 * 65 * 4];
  int bid = blockIdx.x;
  if (bid < 256)       dev_tc2(saWq, WqTsaH, WqTsaL, 1024, 1024, bid, LDSU);
  else if (bid < 512)  dev_tc2(caWq, WqTcaH, WqTcaL, 1024, 1024, bid - 256, LDSU);
  else if (bid < 768)  dev_tc (saWo, WoTsa, 1024, 1024, bid - 512, LDSU);
  else if (bid < 1024) dev_tc (caWo, WoTca, 1024, 1024, bid - 768, LDSU);
  else if (bid < 2048) dev_tc (W1, W1T, 1024, 4096, bid - 1024, LDSU);
  else                 dev_tc (W2, W2T, 4096, 1024, bid - 2048, LDSU);
}

// ---------------------------------------------------------------------------
// Fused activation pre-pass
// ---------------------------------------------------------------------------
__device__ __forceinline__ void dev_cvt2row(const float* __restrict__ X,
    unsigned short* __restrict__ H, unsigned short* __restrict__ L, int bid)
{
  int i = (bid * 256 + threadIdx.x) * 4;
  f32x4 v = *(const f32x4*)&X[i];
  u16x4 hh, ll;
#pragma unroll
  for (int j = 0; j < 4; j++) {
    unsigned short h = f2bf(v[j]);
    hh[j] = h; ll[j] = f2bf(v[j] - bf2f(h));
  }
  *(u16x4*)&H[i] = hh;
  *(u16x4*)&L[i] = ll;
}

__device__ __forceinline__ void dev_wrel(const float* __restrict__ Wq,
    float* __restrict__ Wr, int bid)
{
  int idx = bid * 256 + threadIdx.x;
  int k = idx >> 4, h = idx & 15;
  const float* src = Wq + (size_t)k * 1024 + h * 64;
  float a = 0.f, s = 0.f;
#pragma unroll
  for (int d = 0; d < 64; d += 4) {
    f32x4 v = *(const f32x4*)&src[d];
#pragma unroll
    for (int j = 0; j < 4; j++) { a += v[j] * (float)(d + j + 1024); s += v[j]; }
  }
  Wr[k * 32 + h] = a;
  Wr[k * 32 + 16 + h] = s;
}

__device__ __forceinline__ void dev_crel(const float* __restrict__ bq,
    float* __restrict__ cr)
{
  int h = threadIdx.x;
  if (h < 16) {
    float a = 0.f, s = 0.f;
    for (int d = 0; d < 64; d++) { float v = bq[h * 64 + d]; a += v * (float)(d + 1024); s += v; }
    cr[h] = a; cr[16 + h] = s;
  }
}

__global__ __launch_bounds__(256) void prep_a_k(
    const float* tgt, const float* mem,
    unsigned short* tgth, unsigned short* tgtl,
    unsigned short* memh, unsigned short* meml,
    const float* saWq, const float* caWq, float* wrelsa, float* wrelca,
    const float* sabq, const float* cabq, float* crelsa, float* crelca)
{
  int bid = blockIdx.x;
  if (bid < 4096)       dev_cvt2row(tgt, tgth, tgtl, bid);
  else if (bid < 8192)  dev_cvt2row(mem, memh, meml, bid - 4096);
  else if (bid < 8256)  dev_wrel(saWq, wrelsa, bid - 8192);
  else if (bid < 8320)  dev_wrel(caWq, wrelca, bid - 8256);
  else if (bid == 8320) dev_crel(sabq, crelsa);
  else                  dev_crel(cabq, crelca);
}

// ---------------------------------------------------------------------------
// rel coefficients mini-GEMM (f32-exact): Out[4096][32] = X[4096][1024]@Wr + cr
// ---------------------------------------------------------------------------
__global__ __launch_bounds__(256) void relgemm_k(const float* __restrict__ X,
    const float* __restrict__ Wr, const float* __restrict__ cr,
    float* __restrict__ Out)
{
  __shared__ float Xs[8][256];
  __shared__ float Ws[256][32];
  int r0 = blockIdx.x * 8;
  int tid = threadIdx.x;
  int rl = tid >> 5, col = tid & 31;
  float acc = 0.f;
  for (int kc = 0; kc < 1024; kc += 256) {
    __syncthreads();
    {
      const float* xs = X + (size_t)(r0 + rl) * 1024 + kc + col * 8;
      *(f32x4*)&Xs[rl][col * 8] = *(const f32x4*)xs;
      *(f32x4*)&Xs[rl][col * 8 + 4] = *(const f32x4*)(xs + 4);
    }
    {
      const float* wsrc = Wr + (size_t)(kc + tid) * 32;
#pragma unroll
      for (int i = 0; i < 8; i++) *(f32x4*)&Ws[tid][i * 4] = *(const f32x4*)&wsrc[i * 4];
    }
    __syncthreads();
#pragma unroll 8
    for (int kk = 0; kk < 256; ++kk) acc += Xs[rl][kk] * Ws[kk][col];
  }
  Out[(size_t)(r0 + rl) * 32 + col] = acc + cr[col];
}

// ---------------------------------------------------------------------------
// Fused attention — R11-proven body VERBATIM. FROZEN.
// ---------------------------------------------------------------------------
template<bool CAUSAL>
__global__ __launch_bounds__(512) void attn_k(
    const unsigned short* __restrict__ Qb, const unsigned short* __restrict__ KVb,
    const float* __restrict__ rAS, unsigned short* __restrict__ Ob)
{
  const int bh = blockIdx.x;
  const int b = bh >> 4, h = bh & 15;
  const int y = blockIdx.y;               // 0..7
  const int tid = threadIdx.x, lane = tid & 63, w = tid >> 6;
  const int g = lane >> 4, li = lane & 15;

  __shared__ __align__(16) unsigned short Kt[64 * 64];   // [k][d] swizzled
  __shared__ __align__(16) unsigned short KT[64 * 64];   // [d][k] swizzled
  __shared__ __align__(16) unsigned short Pl[8][16 * 64];

  const int tile = CAUSAL ? ((w < 4) ? y : (15 - y)) : (2 * y + (w >> 2));
  const int q0 = tile * 64 + (w & 3) * 16;
  const int nkb = CAUSAL ? (16 - y) : 16;

  s16x8 qf[2];
  {
    const unsigned short* qrow = Qb + (size_t)(b * 1024 + q0 + li) * 1024 + h * 64;
    qf[0] = *(const s16x8*)&qrow[8 * g];
    qf[1] = *(const s16x8*)&qrow[8 * g + 32];
  }
  const float SCL2 = 0.125f * 1.44269504f;
  int qri[4];
  float C0c[4], C1c[4], rSc[4], rS1c[4];
#pragma unroll
  for (int r = 0; r < 4; r++) {
    int qr = q0 + 4 * g + r;
    qri[r] = qr;
    float rA = rAS[(size_t)(b * 1024 + qr) * 32 + h];
    float rS = rAS[(size_t)(b * 1024 + qr) * 32 + 16 + h];
    int q1 = (qr + 1 < 1024) ? qr + 1 : 1023;
    float rA1 = rAS[(size_t)(b * 1024 + q1) * 32 + h];
    float rS1 = rAS[(size_t)(b * 1024 + q1) * 32 + 16 + h];
    C0c[r]  = (rA + (float)(qr - 1023) * rS) * SCL2;
    rSc[r]  = rS * SCL2;
    C1c[r]  = (rA1 + (float)(qr + 2) * rS1) * SCL2;
    rS1c[r] = rS1 * SCL2;
  }

  float mrow[4], lrow[4];
#pragma unroll
  for (int r = 0; r < 4; r++) { mrow[r] = -3.0e38f; lrow[r] = 0.f; }
  f32x4 accO[4] = {};

  for (int kbk = 0; kbk < nkb; kbk++) {
    __syncthreads();
    // ---- stage K[k][d] + KT[d][k]: krow = lane, dcols = w*8..w*8+7 ----
    {
      const unsigned short* src = KVb + (size_t)(b * 1024 + kbk * 64 + lane) * 1024 + h * 64 + w * 8;
      s16x8 v = *(const s16x8*)src;
      int slot = w ^ (lane & 7);
      *(s16x8*)&Kt[lane * 64 + slot * 8] = v;
#pragma unroll
      for (int j = 0; j < 8; j++) {
        int d = w * 8 + j;
        KT[d * 64 + (((lane >> 3) ^ (d & 7)) * 8) + (lane & 7)] = (unsigned short)v[j];
      }
    }
    __syncthreads();
    if (!CAUSAL || kbk <= tile) {
      const bool diag = CAUSAL && (kbk == tile);
      // S = Q K^T
      f32x4 accS[4];
#pragma unroll
      for (int nt = 0; nt < 4; nt++) {
        int krow = li + 16 * nt;
        f32x4 c = {};
#pragma unroll
        for (int ks = 0; ks < 2; ks++) {
          int slot = (g + 4 * ks) ^ (krow & 7);
          s16x8 kf = *(const s16x8*)&Kt[krow * 64 + slot * 8];
          c = mfma16(qf[ks], kf, c);
        }
        accS[nt] = c;
      }
      // skew + (diag) mask + online softmax (log2 domain)
      float pv[4][4];
      float bm[4];
#pragma unroll
      for (int r = 0; r < 4; r++) bm[r] = -3.0e38f;
#pragma unroll
      for (int nt = 0; nt < 4; nt++) {
        int kk = kbk * 64 + 16 * nt + li;
        float kkf = (float)kk;
#pragma unroll
        for (int r = 0; r < 4; r++) {
          float sk = (kk <= qri[r]) ? fmaf(kkf, -rSc[r], C0c[r])
                   : ((kk == qri[r] + 1) ? 0.f : fmaf(kkf, -rS1c[r], C1c[r]));
          float lg = fmaf(accS[nt][r], SCL2, sk);
          if (diag && kk > qri[r]) lg = -1.0e9f;
          pv[nt][r] = lg;
          bm[r] = fmaxf(bm[r], lg);
        }
      }
#pragma unroll
      for (int off = 1; off < 16; off <<= 1)
#pragma unroll
        for (int r = 0; r < 4; r++)
          bm[r] = fmaxf(bm[r], __shfl_xor(bm[r], off, 64));
      float scl[4], rsum[4];
#pragma unroll
      for (int r = 0; r < 4; r++) {
        float mnew = fmaxf(mrow[r], bm[r]);
        scl[r] = exp2f(mrow[r] - mnew);
        mrow[r] = mnew;
        rsum[r] = 0.f;
      }
#pragma unroll
      for (int nt = 0; nt < 4; nt++)
#pragma unroll
        for (int r = 0; r < 4; r++) {
          float p = exp2f(pv[nt][r] - mrow[r]);
          pv[nt][r] = p;
          rsum[r] += p;
        }
#pragma unroll
      for (int off = 1; off < 16; off <<= 1)
#pragma unroll
        for (int r = 0; r < 4; r++)
          rsum[r] += __shfl_xor(rsum[r], off, 64);
#pragma unroll
      for (int r = 0; r < 4; r++) lrow[r] = lrow[r] * scl[r] + rsum[r];
      // write P (bf16) to per-wave LDS
#pragma unroll
      for (int nt = 0; nt < 4; nt++)
#pragma unroll
        for (int r = 0; r < 4; r++) {
          int qq = 4 * g + r;
          int kkk = 16 * nt + li;
          int slot = (kkk >> 3) ^ (qq & 7);
          Pl[w][qq * 64 + slot * 8 + (kkk & 7)] = f2bf(pv[nt][r]);
        }
      // rescale O
#pragma unroll
      for (int dt = 0; dt < 4; dt++)
#pragma unroll
        for (int r = 0; r < 4; r++) accO[dt][r] *= scl[r];
      // P fragments (per-wave LDS; same-wave RAW ordering in DS pipe)
      s16x8 pfk[2];
#pragma unroll
      for (int ks = 0; ks < 2; ks++) {
        int slotA = (g + 4 * ks) ^ (li & 7);
        pfk[ks] = *(const s16x8*)&Pl[w][li * 64 + slotA * 8];
      }
      // O += P @ V  (V == K; B-frag from KT[d][k])
#pragma unroll
      for (int dt = 0; dt < 4; dt++) {
#pragma unroll
        for (int ks = 0; ks < 2; ks++) {
          int drow = li + 16 * dt;
          int slotB = (g + 4 * ks) ^ (drow & 7);
          s16x8 vf = *(const s16x8*)&KT[drow * 64 + slotB * 8];
          accO[dt] = mfma16(pfk[ks], vf, accO[dt]);
        }
      }
    }
  }
  // epilogue: O / l -> bf16
  asm volatile("s_nop 7\n\ts_nop 7" :::);
#pragma unroll
  for (int dt = 0; dt < 4; dt++) {
    int dcol = h * 64 + li + 16 * dt;
#pragma unroll
    for (int r = 0; r < 4; r++) {
      int q = q0 + 4 * g + r;
      Ob[(size_t)(b * 1024 + q) * 1024 + dcol] = f2bf(accO[dt][r] / lrow[r]);
    }
  }
}

// ---------------------------------------------------------------------------
// Fused reduce + LN: x = P0 + P1 + bias + resid; O = LN(x); optional bf16
// hi (+lo) copies of O. Replaces ln_k (LN1/LN2/LN3 all use this).
// ---------------------------------------------------------------------------
__global__ __launch_bounds__(256) void redln_k(
    const float* __restrict__ P0, const float* __restrict__ P1,
    const float* __restrict__ bias, const float* __restrict__ resid,
    const float* __restrict__ gw, const float* __restrict__ bw,
    float* __restrict__ O, unsigned short* __restrict__ Obh,
    unsigned short* __restrict__ Obl)
{
  int row = blockIdx.x;
  int tid = threadIdx.x;
  size_t base = (size_t)row * 1024 + tid * 4;
  f32x4 a = *(const f32x4*)&P0[base];
  f32x4 b = *(const f32x4*)&P1[base];
  f32x4 c = *(const f32x4*)&resid[base];
  f32x4 bv = *(const f32x4*)&bias[tid * 4];
  f32x4 v;
#pragma unroll
  for (int j = 0; j < 4; j++) v[j] = a[j] + b[j] + bv[j] + c[j];
  float s = v[0] + v[1] + v[2] + v[3];
  float s2 = v[0]*v[0] + v[1]*v[1] + v[2]*v[2] + v[3]*v[3];
#pragma unroll
  for (int off = 32; off > 0; off >>= 1) {
    s += __shfl_down(s, off, 64);
    s2 += __shfl_down(s2, off, 64);
  }
  __shared__ float rb[8];
  if ((tid & 63) == 0) { rb[tid >> 6] = s; rb[4 + (tid >> 6)] = s2; }
  __syncthreads();
  float S = rb[0] + rb[1] + rb[2] + rb[3];
  float S2 = rb[4] + rb[5] + rb[6] + rb[7];
  float mu = S * (1.f / 1024.f);
  float var = S2 * (1.f / 1024.f) - mu * mu;
  float rstd = rsqrtf(var + 1e-5f);
  f32x4 go = *(const f32x4*)&gw[tid * 4];
  f32x4 bo = *(const f32x4*)&bw[tid * 4];
  f32x4 r;
#pragma unroll
  for (int j = 0; j < 4; j++) r[j] = (v[j] - mu) * rstd * go[j] + bo[j];
  *(f32x4*)&O[base] = r;
  if (Obh) {
    u16x4 oh;
#pragma unroll
    for (int j = 0; j < 4; j++) oh[j] = f2bf(r[j]);
    *(u16x4*)&Obh[base] = oh;
    if (Obl) {
      u16x4 ol;
#pragma unroll
      for (int j = 0; j < 4; j++) ol[j] = f2bf(r[j] - bf2f(f2bf(r[j])));
      *(u16x4*)&Obl[base] = ol;
    }
  }
}

// ---------------------------------------------------------------------------
extern "C" void kernel_launch(void* const* d_in, const int* in_sizes, int n_in,
                              void* d_out, int out_size, void* d_ws, size_t ws_size,
                              hipStream_t stream)
{
  const float* tgt  = (const float*)d_in[0];
  const float* mem  = (const float*)d_in[1];
  const float* saWq = (const float*)d_in[3];
  const float* sabq = (const float*)d_in[4];
  const float* saWo = (const float*)d_in[5];
  const float* sabo = (const float*)d_in[6];
  const float* caWq = (const float*)d_in[7];
  const float* cabq = (const float*)d_in[8];
  const float* caWo = (const float*)d_in[9];
  const float* cabo = (const float*)d_in[10];
  const float* W1   = (const float*)d_in[11];
  const float* b1   = (const float*)d_in[12];
  const float* W2   = (const float*)d_in[13];
  const float* b2   = (const float*)d_in[14];
  const float* g1   = (const float*)d_in[15];
  const float* be1  = (const float*)d_in[16];
  const float* g2   = (const float*)d_in[17];
  const float* be2  = (const float*)d_in[18];
  const float* g3   = (const float*)d_in[19];
  const float* be3  = (const float*)d_in[20];
  float* out = (float*)d_out;

  char* ws = (char*)d_ws;
  const size_t ACT = (size_t)4096 * 1024;
  unsigned short* RA   = (unsigned short*)ws; ws += ACT * 2;  // tgth -> attnb -> x1h -> attnb -> P1(FFN2,lo)
  unsigned short* RB   = (unsigned short*)ws; ws += ACT * 2;  // tgtl -> x1l -> P1(FFN2,hi)
  unsigned short* qkvb = (unsigned short*)ws; ws += ACT * 2;  // qkv/CAq + P1 span (lo)
  unsigned short* kvb  = (unsigned short*)ws; ws += ACT * 2;  // CAkv + P1 span (hi)
  unsigned short* x2b  = (unsigned short*)ws; ws += ACT * 2;
  unsigned short* RF   = (unsigned short*)ws; ws += (size_t)4096 * 4096 * 2; // memh+meml -> hb
  unsigned short* memh = RF;
  unsigned short* meml = RF + ACT;
  unsigned short* hb   = RF;
  float* Pq = (float*)qkvb;   // 16 MB spanning qkvb+kvb
  float* PR = (float*)RA;     // 16 MB spanning RA+RB
  unsigned short* WqTsaH = (unsigned short*)ws; ws += (size_t)1024 * 1024 * 2;
  unsigned short* WqTsaL = (unsigned short*)ws; ws += (size_t)1024 * 1024 * 2;
  unsigned short* WoTsa  = (unsigned short*)ws; ws += (size_t)1024 * 1024 * 2;
  unsigned short* WqTcaH = (unsigned short*)ws; ws += (size_t)1024 * 1024 * 2;
  unsigned short* WqTcaL = (unsigned short*)ws; ws += (size_t)1024 * 1024 * 2;
  unsigned short* WoTca  = (unsigned short*)ws; ws += (size_t)1024 * 1024 * 2;
  unsigned short* W1T = (unsigned short*)ws; ws += (size_t)4096 * 1024 * 2;
  unsigned short* W2T = (unsigned short*)ws; ws += (size_t)4096 * 1024 * 2;
  float* x2f = (float*)ws; ws += (size_t)4096 * 1024 * 4;
  float* rAS = (float*)ws; ws += (size_t)4096 * 32 * 4;
  float* wrelsa = (float*)ws; ws += (size_t)1024 * 32 * 4;
  float* wrelca = (float*)ws; ws += (size_t)1024 * 32 * 4;
  float* crelsa = (float*)ws; ws += 128;
  float* crelca = (float*)ws; ws += 128;
  float* x1f = out;   // d_out doubles as x1 f32 scratch

  dim3 blk(256);

  // ---------------- fused pre-pass (2 launches) ----------------
  prep_w_k<<<dim3(3072), blk, 0, stream>>>(saWq, caWq, saWo, caWo, W1, W2,
      WqTsaH, WqTsaL, WqTcaH, WqTcaL, WoTsa, WoTca, W1T, W2T);
  prep_a_k<<<dim3(8322), blk, 0, stream>>>(tgt, mem, RA, RB, memh, meml,
      saWq, caWq, wrelsa, wrelca, sabq, cabq, crelsa, crelca);

  // ---------------- main pipeline ----------------
  // SA qkv projection + rel coefs + causal attention
  sgemm_k<<<dim3(256), blk, 0, stream>>>(RA, RB, RA, RB, WqTsaH, WqTsaL, sabq,
      qkvb, qkvb, 1 << 30, 4096, 1024, 1024, 3);
  relgemm_k<<<dim3(512), blk, 0, stream>>>(tgt, wrelsa, crelsa, rAS);
  attn_k<true><<<dim3(64, 8), dim3(512), 0, stream>>>(qkvb, qkvb, rAS, RA);   // attnb = RA
  // SA out-proj split-K (P0=x2f, P1=qkvb span; both dead) + fused LN1
  bgemm_pk<<<dim3(512), blk, 0, stream>>>(RA, WoTsa, x2f, Pq, 4096, 1024, 1024, 512, 3);
  redln_k<<<dim3(4096), blk, 0, stream>>>(x2f, Pq, sabo, tgt, g1, be1, x1f, RA, RB);  // x1h=RA, x1l=RB
  // CA projections merged: q (rows 0..4095, A=x1) + kv (rows 4096.., A=mem)
  sgemm_k<<<dim3(512), blk, 0, stream>>>(RA, RB, memh, meml, WqTcaH, WqTcaL, cabq,
      qkvb, kvb, 4096, 8192, 1024, 1024, 3);
  relgemm_k<<<dim3(512), blk, 0, stream>>>(x1f, wrelca, crelca, rAS);
  attn_k<false><<<dim3(64, 8), dim3(512), 0, stream>>>(qkvb, kvb, rAS, RA);   // attnb = RA
  // CA out-proj split-K (P0=x2f free, P1=qkvb span dead) + fused LN2
  bgemm_pk<<<dim3(512), blk, 0, stream>>>(RA, WoTca, x2f, Pq, 4096, 1024, 1024, 512, 3);
  redln_k<<<dim3(4096), blk, 0, stream>>>(x2f, Pq, cabo, x1f, g2, be2, x2f, x2b, nullptr);
  // FFN1 (hb overwrites memh/meml region — dead after CA kv projection)
  bgemm_k<true, false, true><<<dim3(1024), blk, 0, stream>>>(x2b, W1T, b1, nullptr, hb, 4096, 4096, 1024, 5);
  // FFN2 split-K x2 (P0 <- qkvb span, P1 <- RA span; both dead)
  bgemm_pk<<<dim3(512), blk, 0, stream>>>(hb, W2T, Pq, PR, 4096, 1024, 4096, 2048, 3);
  // fused reduce + LN3 -> out
  redln_k<<<dim3(4096), blk, 0, stream>>>(Pq, PR, b2, x2f, g3, be3, out, nullptr, nullptr);

  (void)in_sizes; (void)n_in; (void)out_size; (void)ws_size;
}

// Round 17
// 415.065 us; speedup vs baseline: 1.1977x; 1.0923x over previous
//
#include <hip/hip_runtime.h>

typedef __attribute__((ext_vector_type(4))) float f32x4;
typedef __attribute__((ext_vector_type(8))) short s16x8;
typedef __attribute__((ext_vector_type(4))) unsigned short u16x4;

__device__ __forceinline__ unsigned short f2bf(float x) {
  union { float f; unsigned u; } un; un.f = x;
  unsigned u = un.u;
  u += 0x7FFFu + ((u >> 16) & 1u);
  return (unsigned short)(u >> 16);
}
__device__ __forceinline__ float bf2f(unsigned short h) {
  union { unsigned u; float f; } un; un.u = ((unsigned)h) << 16; return un.f;
}
__device__ __forceinline__ unsigned short f2h(float x) {
  union { _Float16 h; unsigned short u; } un; un.h = (_Float16)x; return un.u;
}

// Canonical accumulate form: D tied to C ("+v").
__device__ __forceinline__ f32x4 mfma16(s16x8 a, s16x8 b, f32x4 c) {
  asm("v_mfma_f32_16x16x32_bf16 %0, %1, %2, %0" : "+v"(c) : "v"(a), "v"(b));
  return c;
}
__device__ __forceinline__ f32x4 mfma16h(s16x8 a, s16x8 b, f32x4 c) {
  asm("v_mfma_f32_16x16x32_f16 %0, %1, %2, %0" : "+v"(c) : "v"(a), "v"(b));
  return c;
}

__device__ __forceinline__ void gld16(const void* g, void* l) {
  __builtin_amdgcn_global_load_lds(
      (const __attribute__((address_space(1))) void*)g,
      (__attribute__((address_space(3))) void*)l, 16, 0, 0);
}

// ---------------------------------------------------------------------------
// bf16 GEMM, m97-style (R11-proven, unchanged) — used for FFN1.
// ---------------------------------------------------------------------------
template<bool RELU, bool RESID, bool OUT_BF16>
__global__ __launch_bounds__(256, 2) void bgemm_k(
    const unsigned short* __restrict__ Ab, const unsigned short* __restrict__ Bb,
    const float* __restrict__ bias, const float* __restrict__ resid,
    void* __restrict__ Cp, int M, int N, int K, int lbx)
{
  __shared__ __align__(16) unsigned short As[2][128 * 64];
  __shared__ __align__(16) unsigned short Bs[2][128 * 64];

  const int nwg = gridDim.x;
  const int bid = blockIdx.x;
  const int swz = (bid & 7) * (nwg >> 3) + (bid >> 3);
  const int nbx_m1 = (1 << lbx) - 1;
  const int n0 = (swz & nbx_m1) * 128;
  const int m0 = (swz >> lbx) * 128;

  const int tid = threadIdx.x;
  const int lane = tid & 63;
  const int w = tid >> 6;
  const int wm = w >> 1, wn = w & 1;
  const int li = lane & 15, g = lane >> 4;

  f32x4 acc[4][4] = {};

#define STAGE(buf, kt) do { \
    const int k0_ = (kt) * 64; \
    _Pragma("unroll") \
    for (int i_ = 0; i_ < 4; i_++) { \
      int lin = i_ * 256 + tid; int row = lin >> 3; \
      int cg = (lin & 7) ^ (row & 7); \
      gld16(Ab + (size_t)(m0 + row) * K + k0_ + cg * 8, &As[buf][lin * 8]); \
    } \
    _Pragma("unroll") \
    for (int i_ = 0; i_ < 4; i_++) { \
      int lin = i_ * 256 + tid; int row = lin >> 3; \
      int cg = (lin & 7) ^ (row & 7); \
      gld16(Bb + (size_t)(n0 + row) * K + k0_ + cg * 8, &Bs[buf][lin * 8]); \
    } \
  } while (0)

  const int NT = K >> 6;
  STAGE(0, 0);
  for (int t = 0; t < NT; ++t) {
    const int cur = t & 1;
    if (t + 1 < NT) {
      STAGE(cur ^ 1, t + 1);
      asm volatile("s_waitcnt vmcnt(8)" ::: "memory");
    } else {
      asm volatile("s_waitcnt vmcnt(0)" ::: "memory");
    }
    __builtin_amdgcn_sched_barrier(0);
    __builtin_amdgcn_s_barrier();
    __builtin_amdgcn_sched_barrier(0);
#pragma unroll
    for (int ks = 0; ks < 2; ++ks) {
      s16x8 af[4], bf[4];
#pragma unroll
      for (int mt = 0; mt < 4; mt++) {
        int row = wm * 64 + mt * 16 + li;
        int slot = (4 * ks + g) ^ (row & 7);
        af[mt] = *(const s16x8*)&As[cur][row * 64 + slot * 8];
      }
#pragma unroll
      for (int nt = 0; nt < 4; nt++) {
        int row = wn * 64 + nt * 16 + li;
        int slot = (4 * ks + g) ^ (row & 7);
        bf[nt] = *(const s16x8*)&Bs[cur][row * 64 + slot * 8];
      }
#pragma unroll
      for (int mt = 0; mt < 4; mt++)
#pragma unroll
        for (int nt = 0; nt < 4; nt++)
          acc[mt][nt] = mfma16(af[mt], bf[nt], acc[mt][nt]);
    }
    __builtin_amdgcn_sched_barrier(0);
    __builtin_amdgcn_s_barrier();
    __builtin_amdgcn_sched_barrier(0);
  }
#undef STAGE

  asm volatile("s_nop 7\n\ts_nop 7" :::);
#pragma unroll
  for (int mt = 0; mt < 4; mt++) {
    int mrow = m0 + wm * 64 + mt * 16 + 4 * g;
#pragma unroll
    for (int nt = 0; nt < 4; nt++) {
      int ncol = n0 + wn * 64 + nt * 16 + li;
      float bv = bias ? bias[ncol] : 0.f;
#pragma unroll
      for (int r = 0; r < 4; r++) {
        int mr = mrow + r;
        float v = acc[mt][nt][r] + bv;
        if (RESID) v += resid[(size_t)mr * N + ncol];
        if (RELU) v = fmaxf(v, 0.f);
        if (OUT_BF16) ((unsigned short*)Cp)[(size_t)mr * N + ncol] = f2bf(v);
        else          ((float*)Cp)[(size_t)mr * N + ncol] = v;
      }
    }
  }
}

// ---------------------------------------------------------------------------
// Split-K bgemm (R15-proven): blocks with m-tile >= M/128 handle K-range
// [KH,2*KH) and write partial P1; else [0,KH) -> P0. f32 partials.
// ---------------------------------------------------------------------------
__global__ __launch_bounds__(256, 2) void bgemm_pk(
    const unsigned short* __restrict__ Ab, const unsigned short* __restrict__ Bb,
    float* __restrict__ P0, float* __restrict__ P1,
    int M, int N, int K, int KH, int lbx)
{
  __shared__ __align__(16) unsigned short As[2][128 * 64];
  __shared__ __align__(16) unsigned short Bs[2][128 * 64];

  const int nwg = gridDim.x;
  const int bid = blockIdx.x;
  const int swz = (bid & 7) * (nwg >> 3) + (bid >> 3);
  const int nbx_m1 = (1 << lbx) - 1;
  const int n0 = (swz & nbx_m1) * 128;
  int m0 = (swz >> lbx) * 128;

  int kb = 0;
  float* Pp = P0;
  if (m0 >= M) { m0 -= M; kb = KH; Pp = P1; }

  const int tid = threadIdx.x;
  const int lane = tid & 63;
  const int w = tid >> 6;
  const int wm = w >> 1, wn = w & 1;
  const int li = lane & 15, g = lane >> 4;

  f32x4 acc[4][4] = {};

#define PSTAGE(buf, kt) do { \
    const int k0_ = kb + (kt) * 64; \
    _Pragma("unroll") \
    for (int i_ = 0; i_ < 4; i_++) { \
      int lin = i_ * 256 + tid; int row = lin >> 3; \
      int cg = (lin & 7) ^ (row & 7); \
      gld16(Ab + (size_t)(m0 + row) * K + k0_ + cg * 8, &As[buf][lin * 8]); \
    } \
    _Pragma("unroll") \
    for (int i_ = 0; i_ < 4; i_++) { \
      int lin = i_ * 256 + tid; int row = lin >> 3; \
      int cg = (lin & 7) ^ (row & 7); \
      gld16(Bb + (size_t)(n0 + row) * K + k0_ + cg * 8, &Bs[buf][lin * 8]); \
    } \
  } while (0)

  const int NT = KH >> 6;
  PSTAGE(0, 0);
  for (int t = 0; t < NT; ++t) {
    const int cur = t & 1;
    if (t + 1 < NT) {
      PSTAGE(cur ^ 1, t + 1);
      asm volatile("s_waitcnt vmcnt(8)" ::: "memory");
    } else {
      asm volatile("s_waitcnt vmcnt(0)" ::: "memory");
    }
    __builtin_amdgcn_sched_barrier(0);
    __builtin_amdgcn_s_barrier();
    __builtin_amdgcn_sched_barrier(0);
#pragma unroll
    for (int ks = 0; ks < 2; ++ks) {
      s16x8 af[4], bf[4];
#pragma unroll
      for (int mt = 0; mt < 4; mt++) {
        int row = wm * 64 + mt * 16 + li;
        int slot = (4 * ks + g) ^ (row & 7);
        af[mt] = *(const s16x8*)&As[cur][row * 64 + slot * 8];
      }
#pragma unroll
      for (int nt = 0; nt < 4; nt++) {
        int row = wn * 64 + nt * 16 + li;
        int slot = (4 * ks + g) ^ (row & 7);
        bf[nt] = *(const s16x8*)&Bs[cur][row * 64 + slot * 8];
      }
#pragma unroll
      for (int mt = 0; mt < 4; mt++)
#pragma unroll
        for (int nt = 0; nt < 4; nt++)
          acc[mt][nt] = mfma16(af[mt], bf[nt], acc[mt][nt]);
    }
    __builtin_amdgcn_sched_barrier(0);
    __builtin_amdgcn_s_barrier();
    __builtin_amdgcn_sched_barrier(0);
  }
#undef PSTAGE

  asm volatile("s_nop 7\n\ts_nop 7" :::);
#pragma unroll
  for (int mt = 0; mt < 4; mt++) {
    int mrow = m0 + wm * 64 + mt * 16 + 4 * g;
#pragma unroll
    for (int nt = 0; nt < 4; nt++) {
      int ncol = n0 + wn * 64 + nt * 16 + li;
#pragma unroll
      for (int r = 0; r < 4; r++) {
        int mr = mrow + r;
        Pp[(size_t)mr * N + ncol] = acc[mt][nt][r];
      }
    }
  }
}

// ---------------------------------------------------------------------------
// fp16 projection GEMM (R17): bgemm skeleton verbatim + A2/C2 M-stacking +
// f16 MFMA; bf16 output with bias. Replaces split-bf16 sgemm (output is
// bf16-rounded anyway, so fp16 compute error is dominated by that rounding).
// ---------------------------------------------------------------------------
__global__ __launch_bounds__(256, 2) void hgemm_k(
    const unsigned short* __restrict__ Af, const unsigned short* __restrict__ A2f,
    const unsigned short* __restrict__ Bf, const float* __restrict__ bias,
    unsigned short* __restrict__ Cb, unsigned short* __restrict__ C2b,
    int Ms, int M, int N, int K, int lbx)
{
  __shared__ __align__(16) unsigned short As[2][128 * 64];
  __shared__ __align__(16) unsigned short Bs[2][128 * 64];

  const int nwg = gridDim.x;
  const int bid = blockIdx.x;
  const int swz = (bid & 7) * (nwg >> 3) + (bid >> 3);
  const int nbx_m1 = (1 << lbx) - 1;
  const int n0 = (swz & nbx_m1) * 128;
  int m0 = (swz >> lbx) * 128;

  const unsigned short* Ap = Af;
  unsigned short* Cp = Cb;
  if (m0 >= Ms) { Ap = A2f; Cp = C2b; m0 -= Ms; }

  const int tid = threadIdx.x;
  const int lane = tid & 63;
  const int w = tid >> 6;
  const int wm = w >> 1, wn = w & 1;
  const int li = lane & 15, g = lane >> 4;

  f32x4 acc[4][4] = {};

#define HSTAGE(buf, kt) do { \
    const int k0_ = (kt) * 64; \
    _Pragma("unroll") \
    for (int i_ = 0; i_ < 4; i_++) { \
      int lin = i_ * 256 + tid; int row = lin >> 3; \
      int cg = (lin & 7) ^ (row & 7); \
      gld16(Ap + (size_t)(m0 + row) * K + k0_ + cg * 8, &As[buf][lin * 8]); \
    } \
    _Pragma("unroll") \
    for (int i_ = 0; i_ < 4; i_++) { \
      int lin = i_ * 256 + tid; int row = lin >> 3; \
      int cg = (lin & 7) ^ (row & 7); \
      gld16(Bf + (size_t)(n0 + row) * K + k0_ + cg * 8, &Bs[buf][lin * 8]); \
    } \
  } while (0)

  const int NT = K >> 6;
  HSTAGE(0, 0);
  for (int t = 0; t < NT; ++t) {
    const int cur = t & 1;
    if (t + 1 < NT) {
      HSTAGE(cur ^ 1, t + 1);
      asm volatile("s_waitcnt vmcnt(8)" ::: "memory");
    } else {
      asm volatile("s_waitcnt vmcnt(0)" ::: "memory");
    }
    __builtin_amdgcn_sched_barrier(0);
    __builtin_amdgcn_s_barrier();
    __builtin_amdgcn_sched_barrier(0);
#pragma unroll
    for (int ks = 0; ks < 2; ++ks) {
      s16x8 af[4], bf[4];
#pragma unroll
      for (int mt = 0; mt < 4; mt++) {
        int row = wm * 64 + mt * 16 + li;
        int slot = (4 * ks + g) ^ (row & 7);
        af[mt] = *(const s16x8*)&As[cur][row * 64 + slot * 8];
      }
#pragma unroll
      for (int nt = 0; nt < 4; nt++) {
        int row = wn * 64 + nt * 16 + li;
        int slot = (4 * ks + g) ^ (row & 7);
        bf[nt] = *(const s16x8*)&Bs[cur][row * 64 + slot * 8];
      }
#pragma unroll
      for (int mt = 0; mt < 4; mt++)
#pragma unroll
        for (int nt = 0; nt < 4; nt++)
          acc[mt][nt] = mfma16h(af[mt], bf[nt], acc[mt][nt]);
    }
    __builtin_amdgcn_sched_barrier(0);
    __builtin_amdgcn_s_barrier();
    __builtin_amdgcn_sched_barrier(0);
  }
#undef HSTAGE

  asm volatile("s_nop 7\n\ts_nop 7" :::);
#pragma unroll
  for (int mt = 0; mt < 4; mt++) {
    int mrow = m0 + wm * 64 + mt * 16 + 4 * g;
#pragma unroll
    for (int nt = 0; nt < 4; nt++) {
      int ncol = n0 + wn * 64 + nt * 16 + li;
      float bv = bias[ncol];
#pragma unroll
      for (int r = 0; r < 4; r++) {
        int mr = mrow + r;
        Cp[(size_t)mr * N + ncol] = f2bf(acc[mt][nt][r] + bv);
      }
    }
  }
}

// ---------------------------------------------------------------------------
// Fused weight pre-pass (block-range dispatch)
// ---------------------------------------------------------------------------
__device__ __forceinline__ void dev_tc(const float* __restrict__ W,
    unsigned short* __restrict__ WT, int K, int N, int bid, char* ldsu)
{
  unsigned short (*Ls)[65] = (unsigned short (*)[65])ldsu;
  int ntx = N >> 6;
  int ty = bid / ntx, tx = bid - ty * ntx;
  int r0 = ty << 6, c0 = tx << 6;
  int tid = threadIdx.x;
  int rl = tid >> 4, cl = (tid & 15) << 2;
#pragma unroll
  for (int rr = 0; rr < 4; rr++) {
    f32x4 v = *(const f32x4*)&W[(size_t)(r0 + rl + rr * 16) * N + c0 + cl];
#pragma unroll
    for (int j = 0; j < 4; j++) Ls[rl + rr * 16][cl + j] = f2bf(v[j]);
  }
  __syncthreads();
#pragma unroll
  for (int rr = 0; rr < 4; rr++) {
    int nl = rl + rr * 16;
    u16x4 o;
#pragma unroll
    for (int j = 0; j < 4; j++) o[j] = Ls[cl + j][nl];
    *(u16x4*)&WT[(size_t)(c0 + nl) * K + r0 + cl] = o;
  }
}

__device__ __forceinline__ void dev_tcH(const float* __restrict__ W,
    unsigned short* __restrict__ WT, int K, int N, int bid, char* ldsu)
{
  unsigned short (*Ls)[65] = (unsigned short (*)[65])ldsu;
  int ntx = N >> 6;
  int ty = bid / ntx, tx = bid - ty * ntx;
  int r0 = ty << 6, c0 = tx << 6;
  int tid = threadIdx.x;
  int rl = tid >> 4, cl = (tid & 15) << 2;
#pragma unroll
  for (int rr = 0; rr < 4; rr++) {
    f32x4 v = *(const f32x4*)&W[(size_t)(r0 + rl + rr * 16) * N + c0 + cl];
#pragma unroll
    for (int j = 0; j < 4; j++) Ls[rl + rr * 16][cl + j] = f2h(v[j]);
  }
  __syncthreads();
#pragma unroll
  for (int rr = 0; rr < 4; rr++) {
    int nl = rl + rr * 16;
    u16x4 o;
#pragma unroll
    for (int j = 0; j < 4; j++) o[j] = Ls[cl + j][nl];
    *(u16x4*)&WT[(size_t)(c0 + nl) * K + r0 + cl] = o;
  }
}

__global__ __launch_bounds__(256) void prep_w_k(
    const float* saWq, const float* caWq, const float* saWo, const float* caWo,
    const float* W1, const float* W2,
    unsigned short* WqTsaF, unsigned short* WqTcaF,
    unsigned short* WoTsa, unsigned short* WoTca,
    unsigned short* W1T, unsigned short* W2T)
{
  __shared__ __align__(16) char LDSU[64 * 65 * 4];
  int bid = blockIdx.x;
  if (bid < 256)       dev_tcH(saWq, WqTsaF, 1024, 1024, bid, LDSU);
  else if (bid < 512)  dev_tcH(caWq, WqTcaF, 1024, 1024, bid - 256, LDSU);
  else if (bid < 768)  dev_tc (saWo, WoTsa, 1024, 1024, bid - 512, LDSU);
  else if (bid < 1024) dev_tc (caWo, WoTca, 1024, 1024, bid - 768, LDSU);
  else if (bid < 2048) dev_tc (W1, W1T, 1024, 4096, bid - 1024, LDSU);
  else                 dev_tc (W2, W2T, 4096, 1024, bid - 2048, LDSU);
}

// ---------------------------------------------------------------------------
// Fused activation pre-pass (fp16 single-array converts + wrel + crel)
// ---------------------------------------------------------------------------
__device__ __forceinline__ void dev_cvtH(const float* __restrict__ X,
    unsigned short* __restrict__ H, int bid)
{
  int i = (bid * 256 + threadIdx.x) * 4;
  f32x4 v = *(const f32x4*)&X[i];
  u16x4 hh;
#pragma unroll
  for (int j = 0; j < 4; j++) hh[j] = f2h(v[j]);
  *(u16x4*)&H[i] = hh;
}

__device__ __forceinline__ void dev_wrel(const float* __restrict__ Wq,
    float* __restrict__ Wr, int bid)
{
  int idx = bid * 256 + threadIdx.x;
  int k = idx >> 4, h = idx & 15;
  const float* src = Wq + (size_t)k * 1024 + h * 64;
  float a = 0.f, s = 0.f;
#pragma unroll
  for (int d = 0; d < 64; d += 4) {
    f32x4 v = *(const f32x4*)&src[d];
#pragma unroll
    for (int j = 0; j < 4; j++) { a += v[j] * (float)(d + j + 1024); s += v[j]; }
  }
  Wr[k * 32 + h] = a;
  Wr[k * 32 + 16 + h] = s;
}

__device__ __forceinline__ void dev_crel(const float* __restrict__ bq,
    float* __restrict__ cr)
{
  int h = threadIdx.x;
  if (h < 16) {
    float a = 0.f, s = 0.f;
    for (int d = 0; d < 64; d++) { float v = bq[h * 64 + d]; a += v * (float)(d + 1024); s += v; }
    cr[h] = a; cr[16 + h] = s;
  }
}

__global__ __launch_bounds__(256) void prep_a_k(
    const float* tgt, const float* mem,
    unsigned short* tgtf, unsigned short* memf,
    const float* saWq, const float* caWq, float* wrelsa, float* wrelca,
    const float* sabq, const float* cabq, float* crelsa, float* crelca)
{
  int bid = blockIdx.x;
  if (bid < 4096)       dev_cvtH(tgt, tgtf, bid);
  else if (bid < 8192)  dev_cvtH(mem, memf, bid - 4096);
  else if (bid < 8256)  dev_wrel(saWq, wrelsa, bid - 8192);
  else if (bid < 8320)  dev_wrel(caWq, wrelca, bid - 8256);
  else if (bid == 8320) dev_crel(sabq, crelsa);
  else                  dev_crel(cabq, crelca);
}

// ---------------------------------------------------------------------------
// rel coefficients mini-GEMM (f32-exact): Out[4096][32] = X[4096][1024]@Wr + cr
// ---------------------------------------------------------------------------
__global__ __launch_bounds__(256) void relgemm_k(const float* __restrict__ X,
    const float* __restrict__ Wr, const float* __restrict__ cr,
    float* __restrict__ Out)
{
  __shared__ float Xs[8][256];
  __shared__ float Ws[256][32];
  int r0 = blockIdx.x * 8;
  int tid = threadIdx.x;
  int rl = tid >> 5, col = tid & 31;
  float acc = 0.f;
  for (int kc = 0; kc < 1024; kc += 256) {
    __syncthreads();
    {
      const float* xs = X + (size_t)(r0 + rl) * 1024 + kc + col * 8;
      *(f32x4*)&Xs[rl][col * 8] = *(const f32x4*)xs;
      *(f32x4*)&Xs[rl][col * 8 + 4] = *(const f32x4*)(xs + 4);
    }
    {
      const float* wsrc = Wr + (size_t)(kc + tid) * 32;
#pragma unroll
      for (int i = 0; i < 8; i++) *(f32x4*)&Ws[tid][i * 4] = *(const f32x4*)&wsrc[i * 4];
    }
    __syncthreads();
#pragma unroll 8
    for (int kk = 0; kk < 256; ++kk) acc += Xs[rl][kk] * Ws[kk][col];
  }
  Out[(size_t)(r0 + rl) * 32 + col] = acc + cr[col];
}

// ---------------------------------------------------------------------------
// Fused attention — R11-proven body VERBATIM. FROZEN.
// ---------------------------------------------------------------------------
template<bool CAUSAL>
__global__ __launch_bounds__(512) void attn_k(
    const unsigned short* __restrict__ Qb, const unsigned short* __restrict__ KVb,
    const float* __restrict__ rAS, unsigned short* __restrict__ Ob)
{
  const int bh = blockIdx.x;
  const int b = bh >> 4, h = bh & 15;
  const int y = blockIdx.y;               // 0..7
  const int tid = threadIdx.x, lane = tid & 63, w = tid >> 6;
  const int g = lane >> 4, li = lane & 15;

  __shared__ __align__(16) unsigned short Kt[64 * 64];   // [k][d] swizzled
  __shared__ __align__(16) unsigned short KT[64 * 64];   // [d][k] swizzled
  __shared__ __align__(16) unsigned short Pl[8][16 * 64];

  const int tile = CAUSAL ? ((w < 4) ? y : (15 - y)) : (2 * y + (w >> 2));
  const int q0 = tile * 64 + (w & 3) * 16;
  const int nkb = CAUSAL ? (16 - y) : 16;

  s16x8 qf[2];
  {
    const unsigned short* qrow = Qb + (size_t)(b * 1024 + q0 + li) * 1024 + h * 64;
    qf[0] = *(const s16x8*)&qrow[8 * g];
    qf[1] = *(const s16x8*)&qrow[8 * g + 32];
  }
  const float SCL2 = 0.125f * 1.44269504f;
  int qri[4];
  float C0c[4], C1c[4], rSc[4], rS1c[4];
#pragma unroll
  for (int r = 0; r < 4; r++) {
    int qr = q0 + 4 * g + r;
    qri[r] = qr;
    float rA = rAS[(size_t)(b * 1024 + qr) * 32 + h];
    float rS = rAS[(size_t)(b * 1024 + qr) * 32 + 16 + h];
    int q1 = (qr + 1 < 1024) ? qr + 1 : 1023;
    float rA1 = rAS[(size_t)(b * 1024 + q1) * 32 + h];
    float rS1 = rAS[(size_t)(b * 1024 + q1) * 32 + 16 + h];
    C0c[r]  = (rA + (float)(qr - 1023) * rS) * SCL2;
    rSc[r]  = rS * SCL2;
    C1c[r]  = (rA1 + (float)(qr + 2) * rS1) * SCL2;
    rS1c[r] = rS1 * SCL2;
  }

  float mrow[4], lrow[4];
#pragma unroll
  for (int r = 0; r < 4; r++) { mrow[r] = -3.0e38f; lrow[r] = 0.f; }
  f32x4 accO[4] = {};

  for (int kbk = 0; kbk < nkb; kbk++) {
    __syncthreads();
    // ---- stage K[k][d] + KT[d][k]: krow = lane, dcols = w*8..w*8+7 ----
    {
      const unsigned short* src = KVb + (size_t)(b * 1024 + kbk * 64 + lane) * 1024 + h * 64 + w * 8;
      s16x8 v = *(const s16x8*)src;
      int slot = w ^ (lane & 7);
      *(s16x8*)&Kt[lane * 64 + slot * 8] = v;
#pragma unroll
      for (int j = 0; j < 8; j++) {
        int d = w * 8 + j;
        KT[d * 64 + (((lane >> 3) ^ (d & 7)) * 8) + (lane & 7)] = (unsigned short)v[j];
      }
    }
    __syncthreads();
    if (!CAUSAL || kbk <= tile) {
      const bool diag = CAUSAL && (kbk == tile);
      // S = Q K^T
      f32x4 accS[4];
#pragma unroll
      for (int nt = 0; nt < 4; nt++) {
        int krow = li + 16 * nt;
        f32x4 c = {};
#pragma unroll
        for (int ks = 0; ks < 2; ks++) {
          int slot = (g + 4 * ks) ^ (krow & 7);
          s16x8 kf = *(const s16x8*)&Kt[krow * 64 + slot * 8];
          c = mfma16(qf[ks], kf, c);
        }
        accS[nt] = c;
      }
      // skew + (diag) mask + online softmax (log2 domain)
      float pv[4][4];
      float bm[4];
#pragma unroll
      for (int r = 0; r < 4; r++) bm[r] = -3.0e38f;
#pragma unroll
      for (int nt = 0; nt < 4; nt++) {
        int kk = kbk * 64 + 16 * nt + li;
        float kkf = (float)kk;
#pragma unroll
        for (int r = 0; r < 4; r++) {
          float sk = (kk <= qri[r]) ? fmaf(kkf, -rSc[r], C0c[r])
                   : ((kk == qri[r] + 1) ? 0.f : fmaf(kkf, -rS1c[r], C1c[r]));
          float lg = fmaf(accS[nt][r], SCL2, sk);
          if (diag && kk > qri[r]) lg = -1.0e9f;
          pv[nt][r] = lg;
          bm[r] = fmaxf(bm[r], lg);
        }
      }
#pragma unroll
      for (int off = 1; off < 16; off <<= 1)
#pragma unroll
        for (int r = 0; r < 4; r++)
          bm[r] = fmaxf(bm[r], __shfl_xor(bm[r], off, 64));
      float scl[4], rsum[4];
#pragma unroll
      for (int r = 0; r < 4; r++) {
        float mnew = fmaxf(mrow[r], bm[r]);
        scl[r] = exp2f(mrow[r] - mnew);
        mrow[r] = mnew;
        rsum[r] = 0.f;
      }
#pragma unroll
      for (int nt = 0; nt < 4; nt++)
#pragma unroll
        for (int r = 0; r < 4; r++) {
          float p = exp2f(pv[nt][r] - mrow[r]);
          pv[nt][r] = p;
          rsum[r] += p;
        }
#pragma unroll
      for (int off = 1; off < 16; off <<= 1)
#pragma unroll
        for (int r = 0; r < 4; r++)
          rsum[r] += __shfl_xor(rsum[r], off, 64);
#pragma unroll
      for (int r = 0; r < 4; r++) lrow[r] = lrow[r] * scl[r] + rsum[r];
      // write P (bf16) to per-wave LDS
#pragma unroll
      for (int nt = 0; nt < 4; nt++)
#pragma unroll
        for (int r = 0; r < 4; r++) {
          int qq = 4 * g + r;
          int kkk = 16 * nt + li;
          int slot = (kkk >> 3) ^ (qq & 7);
          Pl[w][qq * 64 + slot * 8 + (kkk & 7)] = f2bf(pv[nt][r]);
        }
      // rescale O
#pragma unroll
      for (int dt = 0; dt < 4; dt++)
#pragma unroll
        for (int r = 0; r < 4; r++) accO[dt][r] *= scl[r];
      // P fragments (per-wave LDS; same-wave RAW ordering in DS pipe)
      s16x8 pfk[2];
#pragma unroll
      for (int ks = 0; ks < 2; ks++) {
        int slotA = (g + 4 * ks) ^ (li & 7);
        pfk[ks] = *(const s16x8*)&Pl[w][li * 64 + slotA * 8];
      }
      // O += P @ V  (V == K; B-frag from KT[d][k])
#pragma unroll
      for (int dt = 0; dt < 4; dt++) {
#pragma unroll
        for (int ks = 0; ks < 2; ks++) {
          int drow = li + 16 * dt;
          int slotB = (g + 4 * ks) ^ (drow & 7);
          s16x8 vf = *(const s16x8*)&KT[drow * 64 + slotB * 8];
          accO[dt] = mfma16(pfk[ks], vf, accO[dt]);
        }
      }
    }
  }
  // epilogue: O / l -> bf16
  asm volatile("s_nop 7\n\ts_nop 7" :::);
#pragma unroll
  for (int dt = 0; dt < 4; dt++) {
    int dcol = h * 64 + li + 16 * dt;
#pragma unroll
    for (int r = 0; r < 4; r++) {
      int q = q0 + 4 * g + r;
      Ob[(size_t)(b * 1024 + q) * 1024 + dcol] = f2bf(accO[dt][r] / lrow[r]);
    }
  }
}

// ---------------------------------------------------------------------------
// Fused reduce + LN: x = P0 + P1 + bias + resid; O = LN(x); optional 16-bit
// copy of O (fp16 if F16OUT else bf16) and optional bf16 lo (unused now).
// ---------------------------------------------------------------------------
template<bool F16OUT>
__global__ __launch_bounds__(256) void redln_k(
    const float* __restrict__ P0, const float* __restrict__ P1,
    const float* __restrict__ bias, const float* __restrict__ resid,
    const float* __restrict__ gw, const float* __restrict__ bw,
    float* __restrict__ O, unsigned short* __restrict__ Obh)
{
  int row = blockIdx.x;
  int tid = threadIdx.x;
  size_t base = (size_t)row * 1024 + tid * 4;
  f32x4 a = *(const f32x4*)&P0[base];
  f32x4 b = *(const f32x4*)&P1[base];
  f32x4 c = *(const f32x4*)&resid[base];
  f32x4 bv = *(const f32x4*)&bias[tid * 4];
  f32x4 v;
#pragma unroll
  for (int j = 0; j < 4; j++) v[j] = a[j] + b[j] + bv[j] + c[j];
  float s = v[0] + v[1] + v[2] + v[3];
  float s2 = v[0]*v[0] + v[1]*v[1] + v[2]*v[2] + v[3]*v[3];
#pragma unroll
  for (int off = 32; off > 0; off >>= 1) {
    s += __shfl_down(s, off, 64);
    s2 += __shfl_down(s2, off, 64);
  }
  __shared__ float rb[8];
  if ((tid & 63) == 0) { rb[tid >> 6] = s; rb[4 + (tid >> 6)] = s2; }
  __syncthreads();
  float S = rb[0] + rb[1] + rb[2] + rb[3];
  float S2 = rb[4] + rb[5] + rb[6] + rb[7];
  float mu = S * (1.f / 1024.f);
  float var = S2 * (1.f / 1024.f) - mu * mu;
  float rstd = rsqrtf(var + 1e-5f);
  f32x4 go = *(const f32x4*)&gw[tid * 4];
  f32x4 bo = *(const f32x4*)&bw[tid * 4];
  f32x4 r;
#pragma unroll
  for (int j = 0; j < 4; j++) r[j] = (v[j] - mu) * rstd * go[j] + bo[j];
  *(f32x4*)&O[base] = r;
  if (Obh) {
    u16x4 oh;
#pragma unroll
    for (int j = 0; j < 4; j++) oh[j] = F16OUT ? f2h(r[j]) : f2bf(r[j]);
    *(u16x4*)&Obh[base] = oh;
  }
}

// ---------------------------------------------------------------------------
extern "C" void kernel_launch(void* const* d_in, const int* in_sizes, int n_in,
                              void* d_out, int out_size, void* d_ws, size_t ws_size,
                              hipStream_t stream)
{
  const float* tgt  = (const float*)d_in[0];
  const float* mem  = (const float*)d_in[1];
  const float* saWq = (const float*)d_in[3];
  const float* sabq = (const float*)d_in[4];
  const float* saWo = (const float*)d_in[5];
  const float* sabo = (const float*)d_in[6];
  const float* caWq = (const float*)d_in[7];
  const float* cabq = (const float*)d_in[8];
  const float* caWo = (const float*)d_in[9];
  const float* cabo = (const float*)d_in[10];
  const float* W1   = (const float*)d_in[11];
  const float* b1   = (const float*)d_in[12];
  const float* W2   = (const float*)d_in[13];
  const float* b2   = (const float*)d_in[14];
  const float* g1   = (const float*)d_in[15];
  const float* be1  = (const float*)d_in[16];
  const float* g2   = (const float*)d_in[17];
  const float* be2  = (const float*)d_in[18];
  const float* g3   = (const float*)d_in[19];
  const float* be3  = (const float*)d_in[20];
  float* out = (float*)d_out;

  char* ws = (char*)d_ws;
  const size_t ACT = (size_t)4096 * 1024;
  unsigned short* RA   = (unsigned short*)ws; ws += ACT * 2;  // tgtf -> x1f16 -> P1(FFN2) lo
  unsigned short* RB   = (unsigned short*)ws; ws += ACT * 2;  // memf -> P1(FFN2) hi
  unsigned short* qkvb = (unsigned short*)ws; ws += ACT * 2;  // SA qkv / CA q / Pq lo
  unsigned short* kvb  = (unsigned short*)ws; ws += ACT * 2;  // CA kv / Pq hi
  unsigned short* x2b  = (unsigned short*)ws; ws += ACT * 2;
  unsigned short* RF   = (unsigned short*)ws; ws += (size_t)4096 * 4096 * 2; // attnb / hb
  unsigned short* attb = RF;
  unsigned short* hb   = RF;
  float* Pq = (float*)qkvb;   // 16 MB spanning qkvb+kvb
  float* PR = (float*)RA;     // 16 MB spanning RA+RB
  unsigned short* WqTsaF = (unsigned short*)ws; ws += (size_t)1024 * 1024 * 2;
  unsigned short* WqTcaF = (unsigned short*)ws; ws += (size_t)1024 * 1024 * 2;
  unsigned short* WoTsa  = (unsigned short*)ws; ws += (size_t)1024 * 1024 * 2;
  unsigned short* WoTca  = (unsigned short*)ws; ws += (size_t)1024 * 1024 * 2;
  unsigned short* W1T = (unsigned short*)ws; ws += (size_t)4096 * 1024 * 2;
  unsigned short* W2T = (unsigned short*)ws; ws += (size_t)4096 * 1024 * 2;
  float* x2f = (float*)ws; ws += (size_t)4096 * 1024 * 4;
  float* rAS = (float*)ws; ws += (size_t)4096 * 32 * 4;
  float* wrelsa = (float*)ws; ws += (size_t)1024 * 32 * 4;
  float* wrelca = (float*)ws; ws += (size_t)1024 * 32 * 4;
  float* crelsa = (float*)ws; ws += 128;
  float* crelca = (float*)ws; ws += 128;
  float* x1f = out;   // d_out doubles as x1 f32 scratch

  dim3 blk(256);

  // ---------------- fused pre-pass (2 launches) ----------------
  prep_w_k<<<dim3(3072), blk, 0, stream>>>(saWq, caWq, saWo, caWo, W1, W2,
      WqTsaF, WqTcaF, WoTsa, WoTca, W1T, W2T);
  prep_a_k<<<dim3(8322), blk, 0, stream>>>(tgt, mem, RA, RB,
      saWq, caWq, wrelsa, wrelca, sabq, cabq, crelsa, crelca);

  // ---------------- main pipeline ----------------
  // SA qkv projection (fp16 GEMM) + rel coefs + causal attention
  hgemm_k<<<dim3(256), blk, 0, stream>>>(RA, RA, WqTsaF, sabq,
      qkvb, qkvb, 1 << 30, 4096, 1024, 1024, 3);
  relgemm_k<<<dim3(512), blk, 0, stream>>>(tgt, wrelsa, crelsa, rAS);
  attn_k<true><<<dim3(64, 8), dim3(512), 0, stream>>>(qkvb, qkvb, rAS, attb);
  // SA out-proj split-K + fused LN1 (x1 f32 -> out scratch; x1 fp16 -> RA)
  bgemm_pk<<<dim3(512), blk, 0, stream>>>(attb, WoTsa, x2f, Pq, 4096, 1024, 1024, 512, 3);
  redln_k<true><<<dim3(4096), blk, 0, stream>>>(x2f, Pq, sabo, tgt, g1, be1, x1f, RA);
  // CA projections merged: q (rows 0..4095, A=x1 fp16) + kv (rows 4096.., A=mem fp16)
  hgemm_k<<<dim3(512), blk, 0, stream>>>(RA, RB, WqTcaF, cabq,
      qkvb, kvb, 4096, 8192, 1024, 1024, 3);
  relgemm_k<<<dim3(512), blk, 0, stream>>>(x1f, wrelca, crelca, rAS);
  attn_k<false><<<dim3(64, 8), dim3(512), 0, stream>>>(qkvb, kvb, rAS, attb);
  // CA out-proj split-K + fused LN2 (x2 f32 -> x2f; x2 bf16 -> x2b)
  bgemm_pk<<<dim3(512), blk, 0, stream>>>(attb, WoTca, x2f, Pq, 4096, 1024, 1024, 512, 3);
  redln_k<false><<<dim3(4096), blk, 0, stream>>>(x2f, Pq, cabo, x1f, g2, be2, x2f, x2b);
  // FFN1 (hb overwrites attnb region — dead after CA out-proj)
  bgemm_k<true, false, true><<<dim3(1024), blk, 0, stream>>>(x2b, W1T, b1, nullptr, hb, 4096, 4096, 1024, 5);
  // FFN2 split-K x2 (Pq <- qkvb span, PR <- RA span; both dead)
  bgemm_pk<<<dim3(512), blk, 0, stream>>>(hb, W2T, Pq, PR, 4096, 1024, 4096, 2048, 3);
  // fused reduce + LN3 -> out
  redln_k<false><<<dim3(4096), blk, 0, stream>>>(Pq, PR, b2, x2f, g3, be3, out, nullptr);

  (void)in_sizes; (void)n_in; (void)out_size; (void)ws_size;
}

// Round 19
// 402.596 us; speedup vs baseline: 1.2348x; 1.0310x over previous
//
#include <hip/hip_runtime.h>

typedef __attribute__((ext_vector_type(4))) float f32x4;
typedef __attribute__((ext_vector_type(8))) short s16x8;
typedef __attribute__((ext_vector_type(4))) unsigned short u16x4;

__device__ __forceinline__ unsigned short f2bf(float x) {
  union { float f; unsigned u; } un; un.f = x;
  unsigned u = un.u;
  u += 0x7FFFu + ((u >> 16) & 1u);
  return (unsigned short)(u >> 16);
}
__device__ __forceinline__ float bf2f(unsigned short h) {
  union { unsigned u; float f; } un; un.u = ((unsigned)h) << 16; return un.f;
}
__device__ __forceinline__ unsigned short f2h(float x) {
  union { _Float16 h; unsigned short u; } un; un.h = (_Float16)x; return un.u;
}

// Canonical accumulate form: D tied to C ("+v").
__device__ __forceinline__ f32x4 mfma16(s16x8 a, s16x8 b, f32x4 c) {
  asm("v_mfma_f32_16x16x32_bf16 %0, %1, %2, %0" : "+v"(c) : "v"(a), "v"(b));
  return c;
}
__device__ __forceinline__ f32x4 mfma16h(s16x8 a, s16x8 b, f32x4 c) {
  asm("v_mfma_f32_16x16x32_f16 %0, %1, %2, %0" : "+v"(c) : "v"(a), "v"(b));
  return c;
}

__device__ __forceinline__ void gld16(const void* g, void* l) {
  __builtin_amdgcn_global_load_lds(
      (const __attribute__((address_space(1))) void*)g,
      (__attribute__((address_space(3))) void*)l, 16, 0, 0);
}

// ---------------------------------------------------------------------------
// bf16 GEMM, m97-style (R11-proven, unchanged) — used for FFN1.
// ---------------------------------------------------------------------------
template<bool RELU, bool RESID, bool OUT_BF16>
__global__ __launch_bounds__(256, 2) void bgemm_k(
    const unsigned short* __restrict__ Ab, const unsigned short* __restrict__ Bb,
    const float* __restrict__ bias, const float* __restrict__ resid,
    void* __restrict__ Cp, int M, int N, int K, int lbx)
{
  __shared__ __align__(16) unsigned short As[2][128 * 64];
  __shared__ __align__(16) unsigned short Bs[2][128 * 64];

  const int nwg = gridDim.x;
  const int bid = blockIdx.x;
  const int swz = (bid & 7) * (nwg >> 3) + (bid >> 3);
  const int nbx_m1 = (1 << lbx) - 1;
  const int n0 = (swz & nbx_m1) * 128;
  const int m0 = (swz >> lbx) * 128;

  const int tid = threadIdx.x;
  const int lane = tid & 63;
  const int w = tid >> 6;
  const int wm = w >> 1, wn = w & 1;
  const int li = lane & 15, g = lane >> 4;

  f32x4 acc[4][4] = {};

#define STAGE(buf, kt) do { \
    const int k0_ = (kt) * 64; \
    _Pragma("unroll") \
    for (int i_ = 0; i_ < 4; i_++) { \
      int lin = i_ * 256 + tid; int row = lin >> 3; \
      int cg = (lin & 7) ^ (row & 7); \
      gld16(Ab + (size_t)(m0 + row) * K + k0_ + cg * 8, &As[buf][lin * 8]); \
    } \
    _Pragma("unroll") \
    for (int i_ = 0; i_ < 4; i_++) { \
      int lin = i_ * 256 + tid; int row = lin >> 3; \
      int cg = (lin & 7) ^ (row & 7); \
      gld16(Bb + (size_t)(n0 + row) * K + k0_ + cg * 8, &Bs[buf][lin * 8]); \
    } \
  } while (0)

  const int NT = K >> 6;
  STAGE(0, 0);
  for (int t = 0; t < NT; ++t) {
    const int cur = t & 1;
    if (t + 1 < NT) {
      STAGE(cur ^ 1, t + 1);
      asm volatile("s_waitcnt vmcnt(8)" ::: "memory");
    } else {
      asm volatile("s_waitcnt vmcnt(0)" ::: "memory");
    }
    __builtin_amdgcn_sched_barrier(0);
    __builtin_amdgcn_s_barrier();
    __builtin_amdgcn_sched_barrier(0);
#pragma unroll
    for (int ks = 0; ks < 2; ++ks) {
      s16x8 af[4], bf[4];
#pragma unroll
      for (int mt = 0; mt < 4; mt++) {
        int row = wm * 64 + mt * 16 + li;
        int slot = (4 * ks + g) ^ (row & 7);
        af[mt] = *(const s16x8*)&As[cur][row * 64 + slot * 8];
      }
#pragma unroll
      for (int nt = 0; nt < 4; nt++) {
        int row = wn * 64 + nt * 16 + li;
        int slot = (4 * ks + g) ^ (row & 7);
        bf[nt] = *(const s16x8*)&Bs[cur][row * 64 + slot * 8];
      }
#pragma unroll
      for (int mt = 0; mt < 4; mt++)
#pragma unroll
        for (int nt = 0; nt < 4; nt++)
          acc[mt][nt] = mfma16(af[mt], bf[nt], acc[mt][nt]);
    }
    __builtin_amdgcn_sched_barrier(0);
    __builtin_amdgcn_s_barrier();
    __builtin_amdgcn_sched_barrier(0);
  }
#undef STAGE

  asm volatile("s_nop 7\n\ts_nop 7" :::);
#pragma unroll
  for (int mt = 0; mt < 4; mt++) {
    int mrow = m0 + wm * 64 + mt * 16 + 4 * g;
#pragma unroll
    for (int nt = 0; nt < 4; nt++) {
      int ncol = n0 + wn * 64 + nt * 16 + li;
      float bv = bias ? bias[ncol] : 0.f;
#pragma unroll
      for (int r = 0; r < 4; r++) {
        int mr = mrow + r;
        float v = acc[mt][nt][r] + bv;
        if (RESID) v += resid[(size_t)mr * N + ncol];
        if (RELU) v = fmaxf(v, 0.f);
        if (OUT_BF16) ((unsigned short*)Cp)[(size_t)mr * N + ncol] = f2bf(v);
        else          ((float*)Cp)[(size_t)mr * N + ncol] = v;
      }
    }
  }
}

// ---------------------------------------------------------------------------
// Split-K bgemm (R15-proven)
// ---------------------------------------------------------------------------
__global__ __launch_bounds__(256, 2) void bgemm_pk(
    const unsigned short* __restrict__ Ab, const unsigned short* __restrict__ Bb,
    float* __restrict__ P0, float* __restrict__ P1,
    int M, int N, int K, int KH, int lbx)
{
  __shared__ __align__(16) unsigned short As[2][128 * 64];
  __shared__ __align__(16) unsigned short Bs[2][128 * 64];

  const int nwg = gridDim.x;
  const int bid = blockIdx.x;
  const int swz = (bid & 7) * (nwg >> 3) + (bid >> 3);
  const int nbx_m1 = (1 << lbx) - 1;
  const int n0 = (swz & nbx_m1) * 128;
  int m0 = (swz >> lbx) * 128;

  int kb = 0;
  float* Pp = P0;
  if (m0 >= M) { m0 -= M; kb = KH; Pp = P1; }

  const int tid = threadIdx.x;
  const int lane = tid & 63;
  const int w = tid >> 6;
  const int wm = w >> 1, wn = w & 1;
  const int li = lane & 15, g = lane >> 4;

  f32x4 acc[4][4] = {};

#define PSTAGE(buf, kt) do { \
    const int k0_ = kb + (kt) * 64; \
    _Pragma("unroll") \
    for (int i_ = 0; i_ < 4; i_++) { \
      int lin = i_ * 256 + tid; int row = lin >> 3; \
      int cg = (lin & 7) ^ (row & 7); \
      gld16(Ab + (size_t)(m0 + row) * K + k0_ + cg * 8, &As[buf][lin * 8]); \
    } \
    _Pragma("unroll") \
    for (int i_ = 0; i_ < 4; i_++) { \
      int lin = i_ * 256 + tid; int row = lin >> 3; \
      int cg = (lin & 7) ^ (row & 7); \
      gld16(Bb + (size_t)(n0 + row) * K + k0_ + cg * 8, &Bs[buf][lin * 8]); \
    } \
  } while (0)

  const int NT = KH >> 6;
  PSTAGE(0, 0);
  for (int t = 0; t < NT; ++t) {
    const int cur = t & 1;
    if (t + 1 < NT) {
      PSTAGE(cur ^ 1, t + 1);
      asm volatile("s_waitcnt vmcnt(8)" ::: "memory");
    } else {
      asm volatile("s_waitcnt vmcnt(0)" ::: "memory");
    }
    __builtin_amdgcn_sched_barrier(0);
    __builtin_amdgcn_s_barrier();
    __builtin_amdgcn_sched_barrier(0);
#pragma unroll
    for (int ks = 0; ks < 2; ++ks) {
      s16x8 af[4], bf[4];
#pragma unroll
      for (int mt = 0; mt < 4; mt++) {
        int row = wm * 64 + mt * 16 + li;
        int slot = (4 * ks + g) ^ (row & 7);
        af[mt] = *(const s16x8*)&As[cur][row * 64 + slot * 8];
      }
#pragma unroll
      for (int nt = 0; nt < 4; nt++) {
        int row = wn * 64 + nt * 16 + li;
        int slot = (4 * ks + g) ^ (row & 7);
        bf[nt] = *(const s16x8*)&Bs[cur][row * 64 + slot * 8];
      }
#pragma unroll
      for (int mt = 0; mt < 4; mt++)
#pragma unroll
        for (int nt = 0; nt < 4; nt++)
          acc[mt][nt] = mfma16(af[mt], bf[nt], acc[mt][nt]);
    }
    __builtin_amdgcn_sched_barrier(0);
    __builtin_amdgcn_s_barrier();
    __builtin_amdgcn_sched_barrier(0);
  }
#undef PSTAGE

  asm volatile("s_nop 7\n\ts_nop 7" :::);
#pragma unroll
  for (int mt = 0; mt < 4; mt++) {
    int mrow = m0 + wm * 64 + mt * 16 + 4 * g;
#pragma unroll
    for (int nt = 0; nt < 4; nt++) {
      int ncol = n0 + wn * 64 + nt * 16 + li;
#pragma unroll
      for (int r = 0; r < 4; r++) {
        int mr = mrow + r;
        Pp[(size_t)mr * N + ncol] = acc[mt][nt][r];
      }
    }
  }
}

// ---------------------------------------------------------------------------
// fp16 projection GEMM as device fn (R17 body verbatim; nwg passed in since
// merged wrappers have larger grids). LDS via shared union pointer.
// ---------------------------------------------------------------------------
__device__ __forceinline__ void dev_hgemm(int bid, int nwg,
    const unsigned short* __restrict__ Af, const unsigned short* __restrict__ A2f,
    const unsigned short* __restrict__ Bf, const float* __restrict__ bias,
    unsigned short* __restrict__ Cb, unsigned short* __restrict__ C2b,
    int Ms, int N, int K, int lbx, char* ldsu)
{
  unsigned short (*As)[128 * 64] = (unsigned short (*)[128 * 64])ldsu;
  unsigned short (*Bs)[128 * 64] = (unsigned short (*)[128 * 64])(ldsu + 32768);

  const int swz = (bid & 7) * (nwg >> 3) + (bid >> 3);
  const int nbx_m1 = (1 << lbx) - 1;
  const int n0 = (swz & nbx_m1) * 128;
  int m0 = (swz >> lbx) * 128;

  const unsigned short* Ap = Af;
  unsigned short* Cp = Cb;
  if (m0 >= Ms) { Ap = A2f; Cp = C2b; m0 -= Ms; }

  const int tid = threadIdx.x;
  const int lane = tid & 63;
  const int w = tid >> 6;
  const int wm = w >> 1, wn = w & 1;
  const int li = lane & 15, g = lane >> 4;

  f32x4 acc[4][4] = {};

#define HSTAGE(buf, kt) do { \
    const int k0_ = (kt) * 64; \
    _Pragma("unroll") \
    for (int i_ = 0; i_ < 4; i_++) { \
      int lin = i_ * 256 + tid; int row = lin >> 3; \
      int cg = (lin & 7) ^ (row & 7); \
      gld16(Ap + (size_t)(m0 + row) * K + k0_ + cg * 8, &As[buf][lin * 8]); \
    } \
    _Pragma("unroll") \
    for (int i_ = 0; i_ < 4; i_++) { \
      int lin = i_ * 256 + tid; int row = lin >> 3; \
      int cg = (lin & 7) ^ (row & 7); \
      gld16(Bf + (size_t)(n0 + row) * K + k0_ + cg * 8, &Bs[buf][lin * 8]); \
    } \
  } while (0)

  const int NT = K >> 6;
  HSTAGE(0, 0);
  for (int t = 0; t < NT; ++t) {
    const int cur = t & 1;
    if (t + 1 < NT) {
      HSTAGE(cur ^ 1, t + 1);
      asm volatile("s_waitcnt vmcnt(8)" ::: "memory");
    } else {
      asm volatile("s_waitcnt vmcnt(0)" ::: "memory");
    }
    __builtin_amdgcn_sched_barrier(0);
    __builtin_amdgcn_s_barrier();
    __builtin_amdgcn_sched_barrier(0);
#pragma unroll
    for (int ks = 0; ks < 2; ++ks) {
      s16x8 af[4], bf[4];
#pragma unroll
      for (int mt = 0; mt < 4; mt++) {
        int row = wm * 64 + mt * 16 + li;
        int slot = (4 * ks + g) ^ (row & 7);
        af[mt] = *(const s16x8*)&As[cur][row * 64 + slot * 8];
      }
#pragma unroll
      for (int nt = 0; nt < 4; nt++) {
        int row = wn * 64 + nt * 16 + li;
        int slot = (4 * ks + g) ^ (row & 7);
        bf[nt] = *(const s16x8*)&Bs[cur][row * 64 + slot * 8];
      }
#pragma unroll
      for (int mt = 0; mt < 4; mt++)
#pragma unroll
        for (int nt = 0; nt < 4; nt++)
          acc[mt][nt] = mfma16h(af[mt], bf[nt], acc[mt][nt]);
    }
    __builtin_amdgcn_sched_barrier(0);
    __builtin_amdgcn_s_barrier();
    __builtin_amdgcn_sched_barrier(0);
  }
#undef HSTAGE

  asm volatile("s_nop 7\n\ts_nop 7" :::);
#pragma unroll
  for (int mt = 0; mt < 4; mt++) {
    int mrow = m0 + wm * 64 + mt * 16 + 4 * g;
#pragma unroll
    for (int nt = 0; nt < 4; nt++) {
      int ncol = n0 + wn * 64 + nt * 16 + li;
      float bv = bias[ncol];
#pragma unroll
      for (int r = 0; r < 4; r++) {
        int mr = mrow + r;
        Cp[(size_t)mr * N + ncol] = f2bf(acc[mt][nt][r] + bv);
      }
    }
  }
}

// ---------------------------------------------------------------------------
// rel coefficients mini-GEMM as device fn (f32-exact, body verbatim)
// ---------------------------------------------------------------------------
__device__ __forceinline__ void dev_relgemm(int rbid,
    const float* __restrict__ X, const float* __restrict__ Wr,
    const float* __restrict__ cr, float* __restrict__ Out, char* ldsu)
{
  float (*Xs)[256] = (float (*)[256])ldsu;                 // [8][256]
  float (*Ws)[32]  = (float (*)[32])(ldsu + 8 * 256 * 4);  // [256][32]
  int r0 = rbid * 8;
  int tid = threadIdx.x;
  int rl = tid >> 5, col = tid & 31;
  float acc = 0.f;
  for (int kc = 0; kc < 1024; kc += 256) {
    __syncthreads();
    {
      const float* xs = X + (size_t)(r0 + rl) * 1024 + kc + col * 8;
      *(f32x4*)&Xs[rl][col * 8] = *(const f32x4*)xs;
      *(f32x4*)&Xs[rl][col * 8 + 4] = *(const f32x4*)(xs + 4);
    }
    {
      const float* wsrc = Wr + (size_t)(kc + tid) * 32;
#pragma unroll
      for (int i = 0; i < 8; i++) *(f32x4*)&Ws[tid][i * 4] = *(const f32x4*)&wsrc[i * 4];
    }
    __syncthreads();
#pragma unroll 8
    for (int kk = 0; kk < 256; ++kk) acc += Xs[rl][kk] * Ws[kk][col];
  }
  Out[(size_t)(r0 + rl) * 32 + col] = acc + cr[col];
}

// ---------------------------------------------------------------------------
// Merged wrappers: fp16 projection GEMM + rel mini-GEMM (block-range dispatch)
// ---------------------------------------------------------------------------
__global__ __launch_bounds__(256, 2) void fgemm_sa_k(
    const unsigned short* Af, const unsigned short* Bf, const float* bias,
    unsigned short* Cb,
    const float* X, const float* Wr, const float* cr, float* Out)
{
  __shared__ __align__(16) char LDSU[65536];
  int bid = blockIdx.x;
  if (bid < 256) dev_hgemm(bid, 256, Af, Af, Bf, bias, Cb, Cb, 1 << 30, 1024, 1024, 3, LDSU);
  else           dev_relgemm(bid - 256, X, Wr, cr, Out, LDSU);
}

__global__ __launch_bounds__(256, 2) void fgemm_ca_k(
    const unsigned short* Af, const unsigned short* A2f,
    const unsigned short* Bf, const float* bias,
    unsigned short* Cb, unsigned short* C2b,
    const float* X, const float* Wr, const float* cr, float* Out)
{
  __shared__ __align__(16) char LDSU[65536];
  int bid = blockIdx.x;
  if (bid < 512) dev_hgemm(bid, 512, Af, A2f, Bf, bias, Cb, C2b, 4096, 1024, 1024, 3, LDSU);
  else           dev_relgemm(bid - 512, X, Wr, cr, Out, LDSU);
}

// ---------------------------------------------------------------------------
// Unified pre-pass: weight transposes + activation fp16 converts + wrel + crel
// (all depend only on kernel inputs — single launch, block-range dispatch)
// ---------------------------------------------------------------------------
__device__ __forceinline__ void dev_tc(const float* __restrict__ W,
    unsigned short* __restrict__ WT, int K, int N, int bid, char* ldsu)
{
  unsigned short (*Ls)[65] = (unsigned short (*)[65])ldsu;
  int ntx = N >> 6;
  int ty = bid / ntx, tx = bid - ty * ntx;
  int r0 = ty << 6, c0 = tx << 6;
  int tid = threadIdx.x;
  int rl = tid >> 4, cl = (tid & 15) << 2;
#pragma unroll
  for (int rr = 0; rr < 4; rr++) {
    f32x4 v = *(const f32x4*)&W[(size_t)(r0 + rl + rr * 16) * N + c0 + cl];
#pragma unroll
    for (int j = 0; j < 4; j++) Ls[rl + rr * 16][cl + j] = f2bf(v[j]);
  }
  __syncthreads();
#pragma unroll
  for (int rr = 0; rr < 4; rr++) {
    int nl = rl + rr * 16;
    u16x4 o;
#pragma unroll
    for (int j = 0; j < 4; j++) o[j] = Ls[cl + j][nl];
    *(u16x4*)&WT[(size_t)(c0 + nl) * K + r0 + cl] = o;
  }
}

__device__ __forceinline__ void dev_tcH(const float* __restrict__ W,
    unsigned short* __restrict__ WT, int K, int N, int bid, char* ldsu)
{
  unsigned short (*Ls)[65] = (unsigned short (*)[65])ldsu;
  int ntx = N >> 6;
  int ty = bid / ntx, tx = bid - ty * ntx;
  int r0 = ty << 6, c0 = tx << 6;
  int tid = threadIdx.x;
  int rl = tid >> 4, cl = (tid & 15) << 2;
#pragma unroll
  for (int rr = 0; rr < 4; rr++) {
    f32x4 v = *(const f32x4*)&W[(size_t)(r0 + rl + rr * 16) * N + c0 + cl];
#pragma unroll
    for (int j = 0; j < 4; j++) Ls[rl + rr * 16][cl + j] = f2h(v[j]);
  }
  __syncthreads();
#pragma unroll
  for (int rr = 0; rr < 4; rr++) {
    int nl = rl + rr * 16;
    u16x4 o;
#pragma unroll
    for (int j = 0; j < 4; j++) o[j] = Ls[cl + j][nl];
    *(u16x4*)&WT[(size_t)(c0 + nl) * K + r0 + cl] = o;
  }
}

__device__ __forceinline__ void dev_cvtH(const float* __restrict__ X,
    unsigned short* __restrict__ H, int bid)
{
  int i = (bid * 256 + threadIdx.x) * 4;
  f32x4 v = *(const f32x4*)&X[i];
  u16x4 hh;
#pragma unroll
  for (int j = 0; j < 4; j++) hh[j] = f2h(v[j]);
  *(u16x4*)&H[i] = hh;
}

__device__ __forceinline__ void dev_wrel(const float* __restrict__ Wq,
    float* __restrict__ Wr, int bid)
{
  int idx = bid * 256 + threadIdx.x;
  int k = idx >> 4, h = idx & 15;
  const float* src = Wq + (size_t)k * 1024 + h * 64;
  float a = 0.f, s = 0.f;
#pragma unroll
  for (int d = 0; d < 64; d += 4) {
    f32x4 v = *(const f32x4*)&src[d];
#pragma unroll
    for (int j = 0; j < 4; j++) { a += v[j] * (float)(d + j + 1024); s += v[j]; }
  }
  Wr[k * 32 + h] = a;
  Wr[k * 32 + 16 + h] = s;
}

__device__ __forceinline__ void dev_crel(const float* __restrict__ bq,
    float* __restrict__ cr)
{
  int h = threadIdx.x;
  if (h < 16) {
    float a = 0.f, s = 0.f;
    for (int d = 0; d < 64; d++) { float v = bq[h * 64 + d]; a += v * (float)(d + 1024); s += v; }
    cr[h] = a; cr[16 + h] = s;
  }
}

__global__ __launch_bounds__(256) void prep_all_k(
    const float* saWq, const float* caWq, const float* saWo, const float* caWo,
    const float* W1, const float* W2, const float* tgt, const float* mem,
    unsigned short* WqTsaF, unsigned short* WqTcaF,
    unsigned short* WoTsa, unsigned short* WoTca,
    unsigned short* W1T, unsigned short* W2T,
    unsigned short* tgtf, unsigned short* memf,
    float* wrelsa, float* wrelca,
    const float* sabq, const float* cabq, float* crelsa, float* crelca)
{
  __shared__ __align__(16) char LDSU[64 * 65 * 4];
  int bid = blockIdx.x;
  if (bid < 256)        dev_tcH(saWq, WqTsaF, 1024, 1024, bid, LDSU);
  else if (bid < 512)   dev_tcH(caWq, WqTcaF, 1024, 1024, bid - 256, LDSU);
  else if (bid < 768)   dev_tc (saWo, WoTsa, 1024, 1024, bid - 512, LDSU);
  else if (bid < 1024)  dev_tc (caWo, WoTca, 1024, 1024, bid - 768, LDSU);
  else if (bid < 2048)  dev_tc (W1, W1T, 1024, 4096, bid - 1024, LDSU);
  else if (bid < 3072)  dev_tc (W2, W2T, 4096, 1024, bid - 2048, LDSU);
  else if (bid < 7168)  dev_cvtH(tgt, tgtf, bid - 3072);
  else if (bid < 11264) dev_cvtH(mem, memf, bid - 7168);
  else if (bid < 11328) dev_wrel(saWq, wrelsa, bid - 11264);
  else if (bid < 11392) dev_wrel(caWq, wrelca, bid - 11328);
  else if (bid == 11392) dev_crel(sabq, crelsa);
  else                   dev_crel(cabq, crelca);
}

// ---------------------------------------------------------------------------
// Fused attention — R11-proven body VERBATIM. FROZEN (R7/R8/R10/R12/R18 all
// failed when this kernel was modified in any way).
// ---------------------------------------------------------------------------
template<bool CAUSAL>
__global__ __launch_bounds__(512) void attn_k(
    const unsigned short* __restrict__ Qb, const unsigned short* __restrict__ KVb,
    const float* __restrict__ rAS, unsigned short* __restrict__ Ob)
{
  const int bh = blockIdx.x;
  const int b = bh >> 4, h = bh & 15;
  const int y = blockIdx.y;               // 0..7
  const int tid = threadIdx.x, lane = tid & 63, w = tid >> 6;
  const int g = lane >> 4, li = lane & 15;

  __shared__ __align__(16) unsigned short Kt[64 * 64];   // [k][d] swizzled
  __shared__ __align__(16) unsigned short KT[64 * 64];   // [d][k] swizzled
  __shared__ __align__(16) unsigned short Pl[8][16 * 64];

  const int tile = CAUSAL ? ((w < 4) ? y : (15 - y)) : (2 * y + (w >> 2));
  const int q0 = tile * 64 + (w & 3) * 16;
  const int nkb = CAUSAL ? (16 - y) : 16;

  s16x8 qf[2];
  {
    const unsigned short* qrow = Qb + (size_t)(b * 1024 + q0 + li) * 1024 + h * 64;
    qf[0] = *(const s16x8*)&qrow[8 * g];
    qf[1] = *(const s16x8*)&qrow[8 * g + 32];
  }
  const float SCL2 = 0.125f * 1.44269504f;
  int qri[4];
  float C0c[4], C1c[4], rSc[4], rS1c[4];
#pragma unroll
  for (int r = 0; r < 4; r++) {
    int qr = q0 + 4 * g + r;
    qri[r] = qr;
    float rA = rAS[(size_t)(b * 1024 + qr) * 32 + h];
    float rS = rAS[(size_t)(b * 1024 + qr) * 32 + 16 + h];
    int q1 = (qr + 1 < 1024) ? qr + 1 : 1023;
    float rA1 = rAS[(size_t)(b * 1024 + q1) * 32 + h];
    float rS1 = rAS[(size_t)(b * 1024 + q1) * 32 + 16 + h];
    C0c[r]  = (rA + (float)(qr - 1023) * rS) * SCL2;
    rSc[r]  = rS * SCL2;
    C1c[r]  = (rA1 + (float)(qr + 2) * rS1) * SCL2;
    rS1c[r] = rS1 * SCL2;
  }

  float mrow[4], lrow[4];
#pragma unroll
  for (int r = 0; r < 4; r++) { mrow[r] = -3.0e38f; lrow[r] = 0.f; }
  f32x4 accO[4] = {};

  for (int kbk = 0; kbk < nkb; kbk++) {
    __syncthreads();
    // ---- stage K[k][d] + KT[d][k]: krow = lane, dcols = w*8..w*8+7 ----
    {
      const unsigned short* src = KVb + (size_t)(b * 1024 + kbk * 64 + lane) * 1024 + h * 64 + w * 8;
      s16x8 v = *(const s16x8*)src;
      int slot = w ^ (lane & 7);
      *(s16x8*)&Kt[lane * 64 + slot * 8] = v;
#pragma unroll
      for (int j = 0; j < 8; j++) {
        int d = w * 8 + j;
        KT[d * 64 + (((lane >> 3) ^ (d & 7)) * 8) + (lane & 7)] = (unsigned short)v[j];
      }
    }
    __syncthreads();
    if (!CAUSAL || kbk <= tile) {
      const bool diag = CAUSAL && (kbk == tile);
      // S = Q K^T
      f32x4 accS[4];
#pragma unroll
      for (int nt = 0; nt < 4; nt++) {
        int krow = li + 16 * nt;
        f32x4 c = {};
#pragma unroll
        for (int ks = 0; ks < 2; ks++) {
          int slot = (g + 4 * ks) ^ (krow & 7);
          s16x8 kf = *(const s16x8*)&Kt[krow * 64 + slot * 8];
          c = mfma16(qf[ks], kf, c);
        }
        accS[nt] = c;
      }
      // skew + (diag) mask + online softmax (log2 domain)
      float pv[4][4];
      float bm[4];
#pragma unroll
      for (int r = 0; r < 4; r++) bm[r] = -3.0e38f;
#pragma unroll
      for (int nt = 0; nt < 4; nt++) {
        int kk = kbk * 64 + 16 * nt + li;
        float kkf = (float)kk;
#pragma unroll
        for (int r = 0; r < 4; r++) {
          float sk = (kk <= qri[r]) ? fmaf(kkf, -rSc[r], C0c[r])
                   : ((kk == qri[r] + 1) ? 0.f : fmaf(kkf, -rS1c[r], C1c[r]));
          float lg = fmaf(accS[nt][r], SCL2, sk);
          if (diag && kk > qri[r]) lg = -1.0e9f;
          pv[nt][r] = lg;
          bm[r] = fmaxf(bm[r], lg);
        }
      }
#pragma unroll
      for (int off = 1; off < 16; off <<= 1)
#pragma unroll
        for (int r = 0; r < 4; r++)
          bm[r] = fmaxf(bm[r], __shfl_xor(bm[r], off, 64));
      float scl[4], rsum[4];
#pragma unroll
      for (int r = 0; r < 4; r++) {
        float mnew = fmaxf(mrow[r], bm[r]);
        scl[r] = exp2f(mrow[r] - mnew);
        mrow[r] = mnew;
        rsum[r] = 0.f;
      }
#pragma unroll
      for (int nt = 0; nt < 4; nt++)
#pragma unroll
        for (int r = 0; r < 4; r++) {
          float p = exp2f(pv[nt][r] - mrow[r]);
          pv[nt][r] = p;
          rsum[r] += p;
        }
#pragma unroll
      for (int off = 1; off < 16; off <<= 1)
#pragma unroll
        for (int r = 0; r < 4; r++)
          rsum[r] += __shfl_xor(rsum[r], off, 64);
#pragma unroll
      for (int r = 0; r < 4; r++) lrow[r] = lrow[r] * scl[r] + rsum[r];
      // write P (bf16) to per-wave LDS
#pragma unroll
      for (int nt = 0; nt < 4; nt++)
#pragma unroll
        for (int r = 0; r < 4; r++) {
          int qq = 4 * g + r;
          int kkk = 16 * nt + li;
          int slot = (kkk >> 3) ^ (qq & 7);
          Pl[w][qq * 64 + slot * 8 + (kkk & 7)] = f2bf(pv[nt][r]);
        }
      // rescale O
#pragma unroll
      for (int dt = 0; dt < 4; dt++)
#pragma unroll
        for (int r = 0; r < 4; r++) accO[dt][r] *= scl[r];
      // P fragments (per-wave LDS; same-wave RAW ordering in DS pipe)
      s16x8 pfk[2];
#pragma unroll
      for (int ks = 0; ks < 2; ks++) {
        int slotA = (g + 4 * ks) ^ (li & 7);
        pfk[ks] = *(const s16x8*)&Pl[w][li * 64 + slotA * 8];
      }
      // O += P @ V  (V == K; B-frag from KT[d][k])
#pragma unroll
      for (int dt = 0; dt < 4; dt++) {
#pragma unroll
        for (int ks = 0; ks < 2; ks++) {
          int drow = li + 16 * dt;
          int slotB = (g + 4 * ks) ^ (drow & 7);
          s16x8 vf = *(const s16x8*)&KT[drow * 64 + slotB * 8];
          accO[dt] = mfma16(pfk[ks], vf, accO[dt]);
        }
      }
    }
  }
  // epilogue: O / l -> bf16
  asm volatile("s_nop 7\n\ts_nop 7" :::);
#pragma unroll
  for (int dt = 0; dt < 4; dt++) {
    int dcol = h * 64 + li + 16 * dt;
#pragma unroll
    for (int r = 0; r < 4; r++) {
      int q = q0 + 4 * g + r;
      Ob[(size_t)(b * 1024 + q) * 1024 + dcol] = f2bf(accO[dt][r] / lrow[r]);
    }
  }
}

// ---------------------------------------------------------------------------
// Fused reduce + LN (R16/R17-proven)
// ---------------------------------------------------------------------------
template<bool F16OUT>
__global__ __launch_bounds__(256) void redln_k(
    const float* __restrict__ P0, const float* __restrict__ P1,
    const float* __restrict__ bias, const float* __restrict__ resid,
    const float* __restrict__ gw, const float* __restrict__ bw,
    float* __restrict__ O, unsigned short* __restrict__ Obh)
{
  int row = blockIdx.x;
  int tid = threadIdx.x;
  size_t base = (size_t)row * 1024 + tid * 4;
  f32x4 a = *(const f32x4*)&P0[base];
  f32x4 b = *(const f32x4*)&P1[base];
  f32x4 c = *(const f32x4*)&resid[base];
  f32x4 bv = *(const f32x4*)&bias[tid * 4];
  f32x4 v;
#pragma unroll
  for (int j = 0; j < 4; j++) v[j] = a[j] + b[j] + bv[j] + c[j];
  float s = v[0] + v[1] + v[2] + v[3];
  float s2 = v[0]*v[0] + v[1]*v[1] + v[2]*v[2] + v[3]*v[3];
#pragma unroll
  for (int off = 32; off > 0; off >>= 1) {
    s += __shfl_down(s, off, 64);
    s2 += __shfl_down(s2, off, 64);
  }
  __shared__ float rb[8];
  if ((tid & 63) == 0) { rb[tid >> 6] = s; rb[4 + (tid >> 6)] = s2; }
  __syncthreads();
  float S = rb[0] + rb[1] + rb[2] + rb[3];
  float S2 = rb[4] + rb[5] + rb[6] + rb[7];
  float mu = S * (1.f / 1024.f);
  float var = S2 * (1.f / 1024.f) - mu * mu;
  float rstd = rsqrtf(var + 1e-5f);
  f32x4 go = *(const f32x4*)&gw[tid * 4];
  f32x4 bo = *(const f32x4*)&bw[tid * 4];
  f32x4 r;
#pragma unroll
  for (int j = 0; j < 4; j++) r[j] = (v[j] - mu) * rstd * go[j] + bo[j];
  *(f32x4*)&O[base] = r;
  if (Obh) {
    u16x4 oh;
#pragma unroll
    for (int j = 0; j < 4; j++) oh[j] = F16OUT ? f2h(r[j]) : f2bf(r[j]);
    *(u16x4*)&Obh[base] = oh;
  }
}

// ---------------------------------------------------------------------------
extern "C" void kernel_launch(void* const* d_in, const int* in_sizes, int n_in,
                              void* d_out, int out_size, void* d_ws, size_t ws_size,
                              hipStream_t stream)
{
  const float* tgt  = (const float*)d_in[0];
  const float* mem  = (const float*)d_in[1];
  const float* saWq = (const float*)d_in[3];
  const float* sabq = (const float*)d_in[4];
  const float* saWo = (const float*)d_in[5];
  const float* sabo = (const float*)d_in[6];
  const float* caWq = (const float*)d_in[7];
  const float* cabq = (const float*)d_in[8];
  const float* caWo = (const float*)d_in[9];
  const float* cabo = (const float*)d_in[10];
  const float* W1   = (const float*)d_in[11];
  const float* b1   = (const float*)d_in[12];
  const float* W2   = (const float*)d_in[13];
  const float* b2   = (const float*)d_in[14];
  const float* g1   = (const float*)d_in[15];
  const float* be1  = (const float*)d_in[16];
  const float* g2   = (const float*)d_in[17];
  const float* be2  = (const float*)d_in[18];
  const float* g3   = (const float*)d_in[19];
  const float* be3  = (const float*)d_in[20];
  float* out = (float*)d_out;

  char* ws = (char*)d_ws;
  const size_t ACT = (size_t)4096 * 1024;
  unsigned short* RA   = (unsigned short*)ws; ws += ACT * 2;  // tgtf -> x1f16 -> P1(FFN2) lo
  unsigned short* RB   = (unsigned short*)ws; ws += ACT * 2;  // memf -> P1(FFN2) hi
  unsigned short* qkvb = (unsigned short*)ws; ws += ACT * 2;  // SA qkv / CA q / Pq lo
  unsigned short* kvb  = (unsigned short*)ws; ws += ACT * 2;  // CA kv / Pq hi
  unsigned short* x2b  = (unsigned short*)ws; ws += ACT * 2;  // x2 bf16
  unsigned short* RF   = (unsigned short*)ws; ws += (size_t)4096 * 4096 * 2; // attnb / hb
  unsigned short* attb = RF;
  unsigned short* hb   = RF;
  float* Pq = (float*)qkvb;    // 16 MB spanning qkvb+kvb
  float* PR = (float*)RA;      // 16 MB spanning RA+RB
  unsigned short* WqTsaF = (unsigned short*)ws; ws += (size_t)1024 * 1024 * 2;
  unsigned short* WqTcaF = (unsigned short*)ws; ws += (size_t)1024 * 1024 * 2;
  unsigned short* WoTsa  = (unsigned short*)ws; ws += (size_t)1024 * 1024 * 2;
  unsigned short* WoTca  = (unsigned short*)ws; ws += (size_t)1024 * 1024 * 2;
  unsigned short* W1T = (unsigned short*)ws; ws += (size_t)4096 * 1024 * 2;
  unsigned short* W2T = (unsigned short*)ws; ws += (size_t)4096 * 1024 * 2;
  float* x2f = (float*)ws; ws += (size_t)4096 * 1024 * 4;
  float* rAS = (float*)ws; ws += (size_t)4096 * 32 * 4;
  float* wrelsa = (float*)ws; ws += (size_t)1024 * 32 * 4;
  float* wrelca = (float*)ws; ws += (size_t)1024 * 32 * 4;
  float* crelsa = (float*)ws; ws += 128;
  float* crelca = (float*)ws; ws += 128;
  float* x1f = out;   // d_out doubles as x1 f32 scratch

  dim3 blk(256);

  // ---------------- unified pre-pass (1 launch) ----------------
  prep_all_k<<<dim3(11394), blk, 0, stream>>>(
      saWq, caWq, saWo, caWo, W1, W2, tgt, mem,
      WqTsaF, WqTcaF, WoTsa, WoTca, W1T, W2T,
      RA, RB, wrelsa, wrelca, sabq, cabq, crelsa, crelca);

  // ---------------- main pipeline ----------------
  // SA qkv projection (fp16 GEMM) + rel coefs merged in one launch
  fgemm_sa_k<<<dim3(768), blk, 0, stream>>>(RA, WqTsaF, sabq, qkvb,
      tgt, wrelsa, crelsa, rAS);
  attn_k<true><<<dim3(64, 8), dim3(512), 0, stream>>>(qkvb, qkvb, rAS, attb);
  // SA out-proj split-K + fused LN1 (x1 f32 -> out scratch; x1 fp16 -> RA)
  bgemm_pk<<<dim3(512), blk, 0, stream>>>(attb, WoTsa, x2f, Pq, 4096, 1024, 1024, 512, 3);
  redln_k<true><<<dim3(4096), blk, 0, stream>>>(x2f, Pq, sabo, tgt, g1, be1, x1f, RA);
  // CA projections merged (q rows 0..4095 from x1 fp16; kv rows 4096.. from mem fp16)
  // + CA rel coefs in one launch
  fgemm_ca_k<<<dim3(1024), blk, 0, stream>>>(RA, RB, WqTcaF, cabq, qkvb, kvb,
      x1f, wrelca, crelca, rAS);
  attn_k<false><<<dim3(64, 8), dim3(512), 0, stream>>>(qkvb, kvb, rAS, attb);
  // CA out-proj split-K + fused LN2 (x2 f32 -> x2f; x2 bf16 -> x2b)
  bgemm_pk<<<dim3(512), blk, 0, stream>>>(attb, WoTca, x2f, Pq, 4096, 1024, 1024, 512, 3);
  redln_k<false><<<dim3(4096), blk, 0, stream>>>(x2f, Pq, cabo, x1f, g2, be2, x2f, x2b);
  // FFN1 (hb overwrites attnb region — dead after CA out-proj)
  bgemm_k<true, false, true><<<dim3(1024), blk, 0, stream>>>(x2b, W1T, b1, nullptr, hb, 4096, 4096, 1024, 5);
  // FFN2 split-K x2 (Pq <- qkvb span, PR <- RA span; both dead)
  bgemm_pk<<<dim3(512), blk, 0, stream>>>(hb, W2T, Pq, PR, 4096, 1024, 4096, 2048, 3);
  // fused reduce + LN3 -> out
  redln_k<false><<<dim3(4096), blk, 0, stream>>>(Pq, PR, b2, x2f, g3, be3, out, nullptr);

  (void)in_sizes; (void)n_in; (void)out_size; (void)ws_size;
}